// Round 2
// baseline (795.137 us; speedup 1.0000x reference)
//
#include <hip/hip_runtime.h>

#define NB 8
#define TQv 2048
#define TKv 2048
#define FD 1024
#define HD 1024

typedef __attribute__((ext_vector_type(8))) short short8;
typedef __attribute__((ext_vector_type(8))) _Float16 half8;
typedef __attribute__((ext_vector_type(4))) float f32x4;

// round-to-nearest-even fp32 -> bf16 (finite inputs only)
__device__ __forceinline__ short f2bf(float f) {
    union { float f; unsigned u; } v; v.f = f;
    unsigned r = v.u + 0x7FFFu + ((v.u >> 16) & 1u);
    return (short)(r >> 16);
}

__device__ __forceinline__ half8 as_h8(short8 v) {
    union { short8 s; half8 h; } u; u.s = v; return u.h;
}

// async 16B global -> LDS (global_load_lds_dwordx4); LDS dest = wave-uniform base + lane*16
__device__ __forceinline__ void async16(const short* g, short* l) {
    __builtin_amdgcn_global_load_lds(
        (const __attribute__((address_space(1))) unsigned int*)g,
        (__attribute__((address_space(3))) unsigned int*)l, 16, 0, 0);
}

#define BAR  __builtin_amdgcn_s_barrier()
#define SP1  __builtin_amdgcn_s_setprio(1)
#define SP0  __builtin_amdgcn_s_setprio(0)
#define SCB  __builtin_amdgcn_sched_barrier(0)
#define VMCNT(N) asm volatile("s_waitcnt vmcnt(" #N ")" ::: "memory")
#define LGKC(N)  asm volatile("s_waitcnt lgkmcnt(" #N ")" ::: "memory")

// ===================== 256x256 8-phase GEMM core (T2+T3+T4+T5) =====================
// NT form: C[m][n] = sum_k A[m][k]*B[n][k].  512 threads = 8 waves (2M x 4N);
// per-wave C = 128x64 = acc[8][4] f32x4 frags, 16x16x32 MFMA, BK=64, K-tiles double-buffered.
// LDS 128 KiB: buf{0,1} x { A: 2 halves of [128 rows][64 k], B: same } bf16.
//   XOR swizzle: element (row,k) of a half lives in 16B block L = 8*row + ((k>>3)^(row&7)).
//   Staging is LINEAR in L (global_load_lds constraint); global source is pre-swizzled.
//   Verified round 1: SQ_LDS_BANK_CONFLICT == 0, correctness passed.
//
// ROUND-2 RESTRUCTURE (counted-lgkmcnt, T4 applied to the LDS side):
// Round 1 drained lgkmcnt(0) inside every phase -> reads serialized with MFMA (17% MfmaUtil).
// Now: reads are front-loaded (a0,b0,a1 at P1; b1 at P3), waits are COUNTED and placed
// BEFORE the barrier, one barrier per phase (8/iter, was 16).
//   P1: rd a0,b0,a1 | stg B0(b)   | lgkmcnt(12) (a0,b0 done; a1 in flight) | bar | MFMA a0*b0
//   P2:             | stg B1(b)   | lgkmcnt(0)  (a1 done)                  | bar | MFMA a1*b0
//   P3: rd b1       | stg A0(a+2) |                                          bar | MFMA a0*b1
//   P4:             | stg A1(a+2) | vmcnt(4); lgkmcnt(0) (b1 done)         | bar | MFMA a1*b1
//   P5-P8 mirror on buf1 (stages: B0(a+2), B1(a+2), A0(a+3), A1(a+3)).
// WAR ledger (stage X into region R only after ALL waves' reads of R drained before an
// earlier barrier): a-reads drained pre-BAR2 (LGKC 12/0) -> A stages at P3/P4 safe;
// b0 drained pre-BAR1, b1 pre-BAR4 (LGKC(0)@P4) -> B stages at P5/P6 safe. Mirror likewise.
// vmcnt ledger identical to round 1 (stage schedule unchanged): VMCNT(4) at P4/P8 leaves
// exactly the 2 most recent half-tiles outstanding => the tile computed next is landed;
// barrier after the wait publishes it cross-wave. Last iter: VMCNT(0) at P4.
// sched_barrier(0) pins read-group issue order (so counts are exact) and fences code
// motion across s_barrier (the builtin is not a memory fence for the scheduler).

#define STG_A(BF, H, T) { async16(gA[H][0] + (T)*64, lA[BF][H][0]); \
                          async16(gA[H][1] + (T)*64, lA[BF][H][1]); }
#define STG_B(BF, H, T) { async16(gB[H][0] + (T)*64, lB[BF][H][0]); \
                          async16(gB[H][1] + (T)*64, lB[BF][H][1]); }

#define RD_A(dst, BF, QM) { _Pragma("unroll") for (int ml = 0; ml < 4; ++ml) { \
    dst[ml][0] = *(const short8*)(rdA + (BF)*65536 + ((QM)*64 + ml*16)*128 + o0); \
    dst[ml][1] = *(const short8*)(rdA + (BF)*65536 + ((QM)*64 + ml*16)*128 + o1); } }
#define RD_B(dst, BF, QN) { _Pragma("unroll") for (int nq = 0; nq < 2; ++nq) { \
    dst[nq][0] = *(const short8*)(rdB + (BF)*65536 + ((QN)*32 + nq*16)*128 + o0); \
    dst[nq][1] = *(const short8*)(rdB + (BF)*65536 + ((QN)*32 + nq*16)*128 + o1); } }

#define DO_MFMA(AF, BFR, QM, QN) { \
    _Pragma("unroll") for (int ks = 0; ks < 2; ++ks) \
    _Pragma("unroll") for (int ml = 0; ml < 4; ++ml) \
    _Pragma("unroll") for (int nq = 0; nq < 2; ++nq) { \
        if constexpr (F16) \
            acc[(QM)*4 + ml][(QN)*2 + nq] = __builtin_amdgcn_mfma_f32_16x16x32_f16( \
                as_h8(AF[ml][ks]), as_h8(BFR[nq][ks]), acc[(QM)*4 + ml][(QN)*2 + nq], 0, 0, 0); \
        else \
            acc[(QM)*4 + ml][(QN)*2 + nq] = __builtin_amdgcn_mfma_f32_16x16x32_bf16( \
                AF[ml][ks], BFR[nq][ks], acc[(QM)*4 + ml][(QN)*2 + nq], 0, 0, 0); } }

template <bool F16>
__device__ __forceinline__ void gemm256_core(const short* __restrict__ A,
                                             const short* __restrict__ B,
                                             int ldK, int K, char* smem,
                                             f32x4 acc[8][4], int tid) {
    const int wid = tid >> 6, lane = tid & 63;
    const int wm = wid >> 2, wn = wid & 3;

    // ---- staging setup: thread covers swizzled blocks {tid, tid+512} of each half-tile ----
    const int lr  = wid * 8 + (lane >> 3);              // source row (within 64-row j-window)
    const int kc8 = ((lane & 7) ^ (lane >> 3)) * 8;     // pre-swizzled source k-chunk
    const short* gA[2][2]; const short* gB[2][2];       // [half][j]
    short* lA[2][2][2]; short* lB[2][2][2];             // [buf][half][j]
#pragma unroll
    for (int h = 0; h < 2; ++h)
#pragma unroll
        for (int j = 0; j < 2; ++j) {
            gA[h][j] = A + (size_t)(h * 128 + j * 64 + lr) * ldK + kc8;
            gB[h][j] = B + (size_t)(h * 128 + j * 64 + lr) * ldK + kc8;
#pragma unroll
            for (int bf = 0; bf < 2; ++bf) {
                lA[bf][h][j] = (short*)(smem + bf * 65536 +         h * 16384 + (j * 512 + wid * 64) * 16);
                lB[bf][h][j] = (short*)(smem + bf * 65536 + 32768 + h * 16384 + (j * 512 + wid * 64) * 16);
            }
        }

    // ---- fragment-read setup: A rows from half wm, B rows from half (wn>>1) ----
    const int l15 = lane & 15;
    const int o0 = (((lane >> 4)    ) ^ (lane & 7)) * 16;   // ks=0 swizzled chunk offset
    const int o1 = (((lane >> 4) + 4) ^ (lane & 7)) * 16;   // ks=1
    char* rdA = smem + wm * 16384 + l15 * 128;
    char* rdB = smem + 32768 + (wn >> 1) * 16384 + (wn & 1) * 8192 + l15 * 128;

    // ---- prologue: buf0 full tile0 + buf1 A-halves of tile1; drain tile0 (keep A(t1)) ----
    STG_A(0, 0, 0); STG_A(0, 1, 0); STG_B(0, 0, 0); STG_B(0, 1, 0);
    STG_A(1, 0, 1); STG_A(1, 1, 1);
    VMCNT(4);
    BAR;

    const int nt = K >> 6;
    const int niter = nt >> 1;
    short8 a0[4][2], a1[4][2], b0[2][2], b1[2][2];
    for (int it = 0; it < niter; ++it) {
        const int a = it * 2;
        const bool nolast = (it != niter - 1);
        // P1: reads front-loaded; a1 drains under G1's MFMA
        RD_A(a0, 0, 0); RD_B(b0, 0, 0); SCB;
        RD_A(a1, 0, 1); SCB;
        STG_B(1, 0, a + 1);
        LGKC(12); SCB; BAR; SCB;
        SP1; DO_MFMA(a0, b0, 0, 0); SP0;
        // P2
        STG_B(1, 1, a + 1);
        LGKC(0); SCB; BAR; SCB;
        SP1; DO_MFMA(a1, b0, 1, 0); SP0;
        // P3
        RD_B(b1, 0, 1); SCB;
        if (nolast) STG_A(0, 0, a + 2);
        SCB; BAR; SCB;
        SP1; DO_MFMA(a0, b1, 0, 1); SP0;
        // P4
        if (nolast) { STG_A(0, 1, a + 2); VMCNT(4); } else { VMCNT(0); }
        LGKC(0); SCB; BAR; SCB;
        SP1; DO_MFMA(a1, b1, 1, 1); SP0;
        // P5
        RD_A(a0, 1, 0); RD_B(b0, 1, 0); SCB;
        RD_A(a1, 1, 1); SCB;
        if (nolast) STG_B(0, 0, a + 2);
        LGKC(12); SCB; BAR; SCB;
        SP1; DO_MFMA(a0, b0, 0, 0); SP0;
        // P6
        if (nolast) STG_B(0, 1, a + 2);
        LGKC(0); SCB; BAR; SCB;
        SP1; DO_MFMA(a1, b0, 1, 0); SP0;
        // P7
        RD_B(b1, 1, 1); SCB;
        if (nolast) STG_A(1, 0, a + 3);
        SCB; BAR; SCB;
        SP1; DO_MFMA(a0, b1, 0, 1); SP0;
        // P8
        if (nolast) { STG_A(1, 1, a + 3); VMCNT(4); }
        LGKC(0); SCB; BAR; SCB;
        SP1; DO_MFMA(a1, b1, 1, 1); SP0;
    }
}

// C/D layout per 16x16x32 frag (m89/m91): col = lane&15, row = 4*(lane>>4) + r
// global: row = tile_m + wm*128 + m*16 + 4*(lane>>4) + r ; col = tile_n + wn*64 + n*16 + (lane&15)

// ---- fp32 -> bf16 pre-pass for query & encoder_states ----
__global__ __launch_bounds__(256) void convert_kernel(const float* __restrict__ q,
                                                      const float* __restrict__ e,
                                                      short* __restrict__ xq,
                                                      short* __restrict__ xe) {
    size_t i = (size_t)blockIdx.x * 256 + threadIdx.x;
    const float* src = blockIdx.y ? e : q;
    short* dst = blockIdx.y ? xe : xq;
    float4 a = ((const float4*)src)[2 * i];
    float4 b = ((const float4*)src)[2 * i + 1];
    short8 v;
    v[0] = f2bf(a.x); v[1] = f2bf(a.y); v[2] = f2bf(a.z); v[3] = f2bf(a.w);
    v[4] = f2bf(b.x); v[5] = f2bf(b.y); v[6] = f2bf(b.z); v[7] = f2bf(b.w);
    ((short8*)dst)[i] = v;
}

// ---- W[F][H] fp32 -> Wt[H][F] bf16, z picks Wq/Wk/Wv ----
__global__ __launch_bounds__(256) void wtrans_kernel(const float* __restrict__ Wq,
                                                     const float* __restrict__ Wk,
                                                     const float* __restrict__ Wv,
                                                     short* __restrict__ Wt) {
    __shared__ float tile[32][33];
    const float* W = (blockIdx.z == 0) ? Wq : (blockIdx.z == 1) ? Wk : Wv;
    short* dst = Wt + (size_t)blockIdx.z * HD * FD;
    int h0 = blockIdx.x * 32, f0 = blockIdx.y * 32;
    int tx = threadIdx.x, ty = threadIdx.y;
    for (int j = ty; j < 32; j += 8)
        tile[j][tx] = W[(size_t)(f0 + j) * HD + h0 + tx];
    __syncthreads();
    for (int j = ty; j < 32; j += 8)
        dst[(size_t)(h0 + j) * FD + f0 + tx] = f2bf(tile[tx][j]);
}

// ---- Q/K projections: 256x256 tiles over [16384 x 1024] ----
__global__ __launch_bounds__(512, 2) void projqk_kernel(const short* __restrict__ Xq,
                                                        const short* __restrict__ Xe,
                                                        const short* __restrict__ Wt3,
                                                        const float* __restrict__ bq,
                                                        const float* __restrict__ bk,
                                                        short* __restrict__ Q,
                                                        short* __restrict__ K) {
    extern __shared__ char smem[];
    int tid = threadIdx.x;
    int p = blockIdx.z;
    const short* X = p ? Xe : Xq;
    const short* Wt = Wt3 + (size_t)p * HD * FD;
    const float* bias = p ? bk : bq;
    short* O = p ? K : Q;
    int bid = blockIdx.x;                   // XCD swizzle: m-groups bound to XCDs
    int xcd = bid & 7, idx = bid >> 3;
    int n_t = idx & 3, m_t = (idx >> 2) * 8 + xcd;
    int tile_m = m_t * 256, tile_n = n_t * 256;
    f32x4 acc[8][4] = {};
    gemm256_core<false>(X + (size_t)tile_m * FD, Wt + (size_t)tile_n * FD, FD, FD, smem, acc, tid);
    int wid = tid >> 6, lane = tid & 63;
    int wm = wid >> 2, wn = wid & 3;
    int row0 = tile_m + wm * 128 + ((lane >> 4) << 2);
    int col0 = tile_n + wn * 64 + (lane & 15);
#pragma unroll
    for (int n = 0; n < 4; ++n) {
        int gn = col0 + n * 16;
        float bv_ = bias[gn];
#pragma unroll
        for (int m = 0; m < 8; ++m)
#pragma unroll
            for (int r = 0; r < 4; ++r)
                O[(size_t)(row0 + m * 16 + r) * HD + gn] = f2bf(acc[m][n][r] + bv_);
    }
}

// ---- V projection, transposed natively: Vt[b][h][t] = Wtv[h,:].Xe[b,t,:] + bv[h], fp16 out ----
__global__ __launch_bounds__(512, 2) void projv_kernel(const short* __restrict__ Xe,
                                                       const short* __restrict__ Wtv,
                                                       const float* __restrict__ bv,
                                                       short* __restrict__ Vt) {
    extern __shared__ char smem[];
    int tid = threadIdx.x;
    int bid = blockIdx.x;
    int b = bid & 7, i = bid >> 3;          // batch -> XCD binding
    int m_t = i & 3, n_t = i >> 2;          // m over HD (4), n over TKv (8)
    int tile_m = m_t * 256, tile_n = n_t * 256;
    const short* Xb = Xe + (size_t)b * TKv * FD;
    f32x4 acc[8][4] = {};
    gemm256_core<false>(Wtv + (size_t)tile_m * FD, Xb + (size_t)tile_n * FD, FD, FD, smem, acc, tid);
    short* Ob = Vt + (size_t)b * HD * TKv;
    int wid = tid >> 6, lane = tid & 63;
    int wm = wid >> 2, wn = wid & 3;
    int row0 = tile_m + wm * 128 + ((lane >> 4) << 2);
    int col0 = tile_n + wn * 64 + (lane & 15);
#pragma unroll
    for (int m = 0; m < 8; ++m)
#pragma unroll
        for (int r = 0; r < 4; ++r) {
            int gm = row0 + m * 16 + r;     // h
            float bv_ = bv[gm];
#pragma unroll
            for (int n = 0; n < 4; ++n) {
                union { _Float16 h; short s; } cv;
                cv.h = (_Float16)(acc[m][n][r] + bv_);
                Ob[(size_t)gm * TKv + col0 + n * 16] = cv.s;
            }
        }
}

// ---- mask int32 -> bitmask u64 (ballot), + zero row-sum array L ----
__global__ __launch_bounds__(256) void maskbits_kernel(const int* __restrict__ mask,
                                                       unsigned long long* __restrict__ Mbits,
                                                       float* __restrict__ L) {
    int tid = threadIdx.x;
    int lane = tid & 63;
    if (blockIdx.x < 64) L[blockIdx.x * 256 + tid] = 0.f;
    const int NW = NB * TQv * (TKv / 64);
    int stride = gridDim.x * 4;
    for (int w = blockIdx.x * 4 + (tid >> 6); w < NW; w += stride) {
        int v = mask[(size_t)w * 64 + lane];
        unsigned long long bal = __ballot(v != 0);
        if (lane == 0) Mbits[w] = bal;
    }
}

// ---- score: P' = mask ? exp(QK/32 - 4) : 0 (fp16), row partials -> atomicAdd L ----
__global__ __launch_bounds__(512, 2) void score_kernel(const short* __restrict__ Q,
                                                       const short* __restrict__ K,
                                                       const unsigned long long* __restrict__ Mbits,
                                                       short* __restrict__ S,
                                                       float* __restrict__ L) {
    extern __shared__ char smem[];
    int tid = threadIdx.x;
    int bid = blockIdx.x;
    int b = bid & 7, i = bid >> 3;          // batch -> XCD binding
    int n_t = i & 7, m_t = i >> 3;
    int tile_m = m_t * 256, tile_n = n_t * 256;
    const short* Aq = Q + (size_t)b * TQv * HD;
    const short* Bk = K + (size_t)b * TKv * HD;
    f32x4 acc[8][4] = {};
    gemm256_core<false>(Aq + (size_t)tile_m * HD, Bk + (size_t)tile_n * HD, HD, HD, smem, acc, tid);
    short* Sb = S + (size_t)b * TQv * TKv;
    const unsigned long long* Mb = Mbits + (size_t)b * TQv * (TKv / 64);
    float* Lb = L + (size_t)b * TQv;
    int wid = tid >> 6, lane = tid & 63;
    int wm = wid >> 2, wn = wid & 3;
    int l15 = lane & 15;
    int row0 = tile_m + wm * 128 + ((lane >> 4) << 2);
    int col0 = tile_n + wn * 64 + l15;
    int word = (tile_n + wn * 64) >> 6;
#pragma unroll
    for (int m = 0; m < 8; ++m)
#pragma unroll
        for (int r = 0; r < 4; ++r) {
            int gm = row0 + m * 16 + r;
            unsigned long long bits = Mb[(size_t)gm * (TKv / 64) + word];
            float rs = 0.f;
#pragma unroll
            for (int n = 0; n < 4; ++n) {
                float s = acc[m][n][r] * 0.03125f;
                float pv = ((bits >> (n * 16 + l15)) & 1ULL)
                               ? exp2f((s - 4.0f) * 1.44269504f) : 0.f;
                rs += pv;
                union { _Float16 h; short sh; } cv;
                cv.h = (_Float16)pv;
                Sb[(size_t)gm * TKv + col0 + n * 16] = cv.sh;
            }
            for (int sh = 1; sh < 16; sh <<= 1) rs += __shfl_xor(rs, sh);
            if (l15 == 0) atomicAdd(&Lb[gm], rs);
        }
}

// ---- pv: O = (P' . Vt^T) / L, fp16 MFMA, fp32 out ----
__global__ __launch_bounds__(512, 2) void pv_kernel(const short* __restrict__ P,
                                                    const short* __restrict__ Vt,
                                                    const float* __restrict__ L,
                                                    float* __restrict__ Out) {
    extern __shared__ char smem[];
    int tid = threadIdx.x;
    int bid = blockIdx.x;
    int b = bid & 7, i = bid >> 3;          // batch -> XCD binding
    int n_t = i & 3, m_t = i >> 2;          // n over HD (4), m over TQv (8)
    int tile_m = m_t * 256, tile_n = n_t * 256;
    const short* Ap = P + (size_t)b * TQv * TKv;
    const short* Bv = Vt + (size_t)b * HD * TKv;
    const float* Lb = L + (size_t)b * TQv;
    f32x4 acc[8][4] = {};
    gemm256_core<true>(Ap + (size_t)tile_m * TKv, Bv + (size_t)tile_n * TKv, TKv, TKv, smem, acc, tid);
    float* Ob = Out + (size_t)b * TQv * HD;
    int wid = tid >> 6, lane = tid & 63;
    int wm = wid >> 2, wn = wid & 3;
    int row0 = tile_m + wm * 128 + ((lane >> 4) << 2);
    int col0 = tile_n + wn * 64 + (lane & 15);
#pragma unroll
    for (int m = 0; m < 8; ++m)
#pragma unroll
        for (int r = 0; r < 4; ++r) {
            int gm = row0 + m * 16 + r;
            float l = Lb[gm];
            float inv = (l > 0.f) ? 1.f / l : 0.f;
#pragma unroll
            for (int n = 0; n < 4; ++n)
                Ob[(size_t)gm * HD + col0 + n * 16] = acc[m][n][r] * inv;
        }
}

extern "C" void kernel_launch(void* const* d_in, const int* in_sizes, int n_in,
                              void* d_out, int out_size, void* d_ws, size_t ws_size,
                              hipStream_t stream) {
    const float* query = (const float*)d_in[0];
    const float* enc   = (const float*)d_in[1];
    const int*   mask  = (const int*)d_in[2];
    const float* Wq    = (const float*)d_in[3];
    const float* bq    = (const float*)d_in[4];
    const float* Wk    = (const float*)d_in[5];
    const float* bk    = (const float*)d_in[6];
    const float* Wv    = (const float*)d_in[7];
    const float* bv    = (const float*)d_in[8];
    float* out = (float*)d_out;

    // workspace layout (bytes); total 174,063,616
    //   [0, 6.29MB): Wtq/Wtk/Wtv bf16 (wtrans -> projqk/projv), then reused as
    //     Mbits [0,4MB) + L [4MB,4MB+64KB) once the Wt copies are dead.
    //   S (fp16 P', 67MB) aliases Xq+Xe (dead after projqk/projv).
    char* ws = (char*)d_ws;
    short* Wt  = (short*)(ws);
    unsigned long long* Mbits = (unsigned long long*)(ws);
    float* L   = (float*)(ws + 4194304);
    short* Xq  = (short*)(ws + 6291456);
    short* Xe  = (short*)(ws + 39845888);
    short* S   = (short*)(ws + 6291456);       // aliases Xq,Xe
    short* Qb  = (short*)(ws + 73400320);
    short* Kb  = (short*)(ws + 106954752);
    short* Vt  = (short*)(ws + 140509184);
    (void)in_sizes; (void)n_in; (void)out_size; (void)ws_size;

    // 128 KiB dynamic LDS opt-in (one-time; not a stream op, graph-capture safe)
    static bool inited = false;
    if (!inited) {
        hipFuncSetAttribute((const void*)projqk_kernel, hipFuncAttributeMaxDynamicSharedMemorySize, 131072);
        hipFuncSetAttribute((const void*)projv_kernel,  hipFuncAttributeMaxDynamicSharedMemorySize, 131072);
        hipFuncSetAttribute((const void*)score_kernel,  hipFuncAttributeMaxDynamicSharedMemorySize, 131072);
        hipFuncSetAttribute((const void*)pv_kernel,     hipFuncAttributeMaxDynamicSharedMemorySize, 131072);
        inited = true;
    }

    convert_kernel<<<dim3(8192, 2), 256, 0, stream>>>(query, enc, Xq, Xe);
    wtrans_kernel<<<dim3(32, 32, 3), dim3(32, 8), 0, stream>>>(Wq, Wk, Wv, Wt);
    projqk_kernel<<<dim3(256, 1, 2), 512, 131072, stream>>>(Xq, Xe, Wt, bq, bk, Qb, Kb);
    projv_kernel<<<dim3(256), 512, 131072, stream>>>(Xe, Wt + (size_t)2 * HD * FD, bv, Vt);
    maskbits_kernel<<<dim3(2048), 256, 0, stream>>>(mask, Mbits, L);
    score_kernel<<<dim3(512), 512, 131072, stream>>>(Qb, Kb, Mbits, S, L);
    pv_kernel<<<dim3(256), 512, 131072, stream>>>(S, Vt, L, out);
}

// Round 4
// 624.931 us; speedup vs baseline: 1.2724x; 1.2724x over previous
//
#include <hip/hip_runtime.h>

#define NB 8
#define TQv 2048
#define TKv 2048
#define FD 1024
#define HD 1024

typedef __attribute__((ext_vector_type(8))) short short8;
typedef __attribute__((ext_vector_type(8))) _Float16 half8;
typedef __attribute__((ext_vector_type(4))) float f32x4;

// round-to-nearest-even fp32 -> bf16 (finite inputs only)
__device__ __forceinline__ short f2bf(float f) {
    union { float f; unsigned u; } v; v.f = f;
    unsigned r = v.u + 0x7FFFu + ((v.u >> 16) & 1u);
    return (short)(r >> 16);
}

__device__ __forceinline__ half8 as_h8(short8 v) {
    union { short8 s; half8 h; } u; u.s = v; return u.h;
}

// async 16B global -> LDS (global_load_lds_dwordx4); LDS dest = wave-uniform base + lane*16
__device__ __forceinline__ void async16(const short* g, short* l) {
    __builtin_amdgcn_global_load_lds(
        (const __attribute__((address_space(1))) unsigned int*)g,
        (__attribute__((address_space(3))) unsigned int*)l, 16, 0, 0);
}

// ---- GEMM core: 128x128 tile, 16x16x32 MFMA, 4x4 frags/wave, XOR-swizzled LDS, BK=64 ----
// NT form: C[m][n] = sum_k A[m][k] * Bt[n][k]; 256 threads = 4 waves (2x2 of 64x64).
// ROUND-3/4 RESHAPE (from 32x32x16 / 2x2): 0.5 ds_read_b128 per MFMA instead of 1.0
// (halves LDS read bytes/FLOP -> lifts the LDS-BW cap from ~25% to ~50% MfmaUtil), and
// the 16x16 fragment read is only 2-way bank-aliased (free, m136) instead of 4-way
// (round-0 counter: 2^23 conflict cycles -> expect ~0).
// LDS layout (unchanged, round-0-proven): element (r,k) lives in 16-B block
// L = 8r + ((k>>3) ^ (r&7)), byte (k&7)*2.
//   - staging call = 64 consecutive blocks = 8 rows x 8 chunks; lane l takes
//     row lr=l>>3, chunk kc=(l&7)^lr -> per row 128 contiguous global bytes (coalesced).
//   - frag read (16 rows, k-chunk c=ks*4+(lane>>4)): block%8 = c^(r&7) sweeps all 8
//     values over 8 rows; lanes l15 and l15+8 alias (2-way, free).
template <bool F16>
__device__ __forceinline__ void gemm128_core(const short* __restrict__ A, int lda,
                                             const short* __restrict__ B, int ldb,
                                             int K, short* As, short* Bs,
                                             f32x4 acc[4][4], int tid) {
    int wave = tid >> 6, lane = tid & 63;
    int lr = lane >> 3;                // row within 8-row window
    int kc = (lane & 7) ^ lr;          // swizzled chunk this lane fetches
    const short* ga[4]; const short* gb[4];
    short* la[4]; short* lb[4];
#pragma unroll
    for (int j = 0; j < 4; ++j) {
        int w = wave + 4 * j;          // window index 0..15 (8 rows each)
        ga[j] = A + (size_t)(8 * w + lr) * lda + kc * 8;
        gb[j] = B + (size_t)(8 * w + lr) * ldb + kc * 8;
        la[j] = As + w * 512;          // 64 blocks * 8 shorts
        lb[j] = Bs + w * 512;
    }
    int l15 = lane & 15;
    int g4 = lane >> 4;                // k-chunk selector within a k-step (0..3)
    int r7 = l15 & 7;                  // row&7 for all of this lane's fragment rows
    const short* aB = As + ((wave & 1) * 64 + l15) * 64;   // row stride = 64 shorts
    const short* bB = Bs + ((wave >> 1) * 64 + l15) * 64;
    int o0 = ((g4    ) ^ r7) * 8;      // ks=0: chunks 0..3
    int o1 = ((g4 + 4) ^ r7) * 8;      // ks=1: chunks 4..7

    for (int k0 = 0; k0 < K; k0 += 64) {
        __syncthreads();
#pragma unroll
        for (int j = 0; j < 4; ++j) { async16(ga[j], la[j]); async16(gb[j], lb[j]); }
#pragma unroll
        for (int j = 0; j < 4; ++j) { ga[j] += 64; gb[j] += 64; }
        __syncthreads();
#pragma unroll
        for (int ks = 0; ks < 2; ++ks) {
            int oo = ks ? o1 : o0;
            short8 af[4], bf[4];
#pragma unroll
            for (int f = 0; f < 4; ++f) {
                af[f] = *(const short8*)(aB + f * 1024 + oo);   // f*16 rows * 64 shorts
                bf[f] = *(const short8*)(bB + f * 1024 + oo);
            }
#pragma unroll
            for (int mf = 0; mf < 4; ++mf)
#pragma unroll
                for (int nf = 0; nf < 4; ++nf) {
                    if constexpr (F16)
                        acc[mf][nf] = __builtin_amdgcn_mfma_f32_16x16x32_f16(
                            as_h8(af[mf]), as_h8(bf[nf]), acc[mf][nf], 0, 0, 0);
                    else
                        acc[mf][nf] = __builtin_amdgcn_mfma_f32_16x16x32_bf16(
                            af[mf], bf[nf], acc[mf][nf], 0, 0, 0);
                }
        }
    }
}

// C/D layout per 16x16x32 frag (m89/m91): col = lane&15, row = 4*(lane>>4) + r
#define EGM(mf, r) (tile_m + (wave & 1) * 64 + (mf) * 16 + ((lane >> 4) << 2) + (r))
#define EGN(nf)    (tile_n + (wave >> 1) * 64 + (nf) * 16 + (lane & 15))

// ---- fp32 -> bf16 pre-pass for query & encoder_states ----
__global__ __launch_bounds__(256) void convert_kernel(const float* __restrict__ q,
                                                      const float* __restrict__ e,
                                                      short* __restrict__ xq,
                                                      short* __restrict__ xe) {
    size_t i = (size_t)blockIdx.x * 256 + threadIdx.x;
    const float* src = blockIdx.y ? e : q;
    short* dst = blockIdx.y ? xe : xq;
    float4 a = ((const float4*)src)[2 * i];
    float4 b = ((const float4*)src)[2 * i + 1];
    short8 v;
    v[0] = f2bf(a.x); v[1] = f2bf(a.y); v[2] = f2bf(a.z); v[3] = f2bf(a.w);
    v[4] = f2bf(b.x); v[5] = f2bf(b.y); v[6] = f2bf(b.z); v[7] = f2bf(b.w);
    ((short8*)dst)[i] = v;
}

// ---- W[F][H] fp32 -> Wt[H][F] bf16, z picks Wq/Wk/Wv ----
__global__ __launch_bounds__(256) void wtrans_kernel(const float* __restrict__ Wq,
                                                     const float* __restrict__ Wk,
                                                     const float* __restrict__ Wv,
                                                     short* __restrict__ Wt) {
    __shared__ float tile[32][33];
    const float* W = (blockIdx.z == 0) ? Wq : (blockIdx.z == 1) ? Wk : Wv;
    short* dst = Wt + (size_t)blockIdx.z * HD * FD;
    int h0 = blockIdx.x * 32, f0 = blockIdx.y * 32;
    int tx = threadIdx.x, ty = threadIdx.y;
    for (int j = ty; j < 32; j += 8)
        tile[j][tx] = W[(size_t)(f0 + j) * HD + h0 + tx];
    __syncthreads();
    for (int j = ty; j < 32; j += 8)
        dst[(size_t)(h0 + j) * FD + f0 + tx] = f2bf(tile[tx][j]);
}

// ---- Q/K projections ----
__global__ __launch_bounds__(256, 3) void projqk_kernel(const short* __restrict__ Xq,
                                                        const short* __restrict__ Xe,
                                                        const short* __restrict__ Wt3,
                                                        const float* __restrict__ bq,
                                                        const float* __restrict__ bk,
                                                        short* __restrict__ Q,
                                                        short* __restrict__ K) {
    __shared__ short As[128 * 64];
    __shared__ short Bs[128 * 64];
    int tid = threadIdx.x;
    int wave = tid >> 6, lane = tid & 63;
    int p = blockIdx.z;
    const short* X = (p == 0) ? Xq : Xe;
    const short* Wt = Wt3 + (size_t)p * HD * FD;
    const float* bias = (p == 0) ? bq : bk;
    short* O = (p == 0) ? Q : K;
    int bid = blockIdx.x;              // XCD swizzle: m-groups bound to XCDs
    int xcd = bid & 7;
    int idx = bid >> 3;
    int n_t = idx & 7;
    int m_t = (idx >> 3) * 8 + xcd;
    int tile_m = m_t * 128;
    int tile_n = n_t * 128;
    f32x4 acc[4][4] = {};
    gemm128_core<false>(X + (size_t)tile_m * FD, FD, Wt + (size_t)tile_n * FD, FD, FD,
                        As, Bs, acc, tid);
#pragma unroll
    for (int nf = 0; nf < 4; ++nf) {
        int gn = EGN(nf);
        float bv_ = bias[gn];
#pragma unroll
        for (int mf = 0; mf < 4; ++mf)
#pragma unroll
            for (int r = 0; r < 4; ++r)
                O[(size_t)EGM(mf, r) * HD + gn] = f2bf(acc[mf][nf][r] + bv_);
    }
}

// ---- V projection, transposed natively: Vt[b][h][t] = Wtv[h,:].Xe[b,t,:] + bv[h], fp16 out ----
__global__ __launch_bounds__(256, 3) void projv_kernel(const short* __restrict__ Xe,
                                                       const short* __restrict__ Wtv,
                                                       const float* __restrict__ bv,
                                                       short* __restrict__ Vt) {
    __shared__ short As[128 * 64];
    __shared__ short Bs[128 * 64];
    int tid = threadIdx.x;
    int wave = tid >> 6, lane = tid & 63;
    int id = blockIdx.x;
    int b = id & 7;                    // batch -> XCD binding
    int i = id >> 3;
    int n_t = i & 15;                  // over TKv
    int m_t = i >> 4;                  // over HD
    int tile_m = m_t * 128;
    int tile_n = n_t * 128;
    const short* Xb = Xe + (size_t)b * TKv * FD;
    f32x4 acc[4][4] = {};
    gemm128_core<false>(Wtv + (size_t)tile_m * FD, FD, Xb + (size_t)tile_n * FD, FD, FD,
                        As, Bs, acc, tid);
    short* Ob = Vt + (size_t)b * HD * TKv;
#pragma unroll
    for (int mf = 0; mf < 4; ++mf)
#pragma unroll
        for (int r = 0; r < 4; ++r) {
            int gm = EGM(mf, r);        // h
            float bv_ = bv[gm];
#pragma unroll
            for (int nf = 0; nf < 4; ++nf) {
                union { _Float16 h; short s; } cv;
                cv.h = (_Float16)(acc[mf][nf][r] + bv_);
                Ob[(size_t)gm * TKv + EGN(nf)] = cv.s;
            }
        }
}

// ---- mask int32 -> bitmask u64 (ballot), + zero row-sum array L ----
__global__ __launch_bounds__(256) void maskbits_kernel(const int* __restrict__ mask,
                                                       unsigned long long* __restrict__ Mbits,
                                                       float* __restrict__ L) {
    int tid = threadIdx.x;
    int lane = tid & 63;
    if (blockIdx.x < 64) L[blockIdx.x * 256 + tid] = 0.f;
    const int NW = NB * TQv * (TKv / 64);
    int stride = gridDim.x * 4;
    for (int w = blockIdx.x * 4 + (tid >> 6); w < NW; w += stride) {
        int v = mask[(size_t)w * 64 + lane];
        unsigned long long bal = __ballot(v != 0);
        if (lane == 0) Mbits[w] = bal;
    }
}

// ---- score: P' = mask ? exp(QK/32 - 4) : 0 (fp16), row partials -> atomicAdd L ----
__global__ __launch_bounds__(256, 3) void score_kernel(const short* __restrict__ Q,
                                                       const short* __restrict__ K,
                                                       const unsigned long long* __restrict__ Mbits,
                                                       short* __restrict__ S,
                                                       float* __restrict__ L) {
    __shared__ short As[128 * 64];
    __shared__ short Bs[128 * 64];
    int tid = threadIdx.x;
    int wave = tid >> 6, lane = tid & 63;
    int id = blockIdx.x;
    int b = id & 7;                    // batch -> XCD binding
    int i = id >> 3;
    int n_t = i & 15;
    int m_t = i >> 4;
    int tile_m = m_t * 128;
    int tile_n = n_t * 128;
    const short* Aq = Q + (size_t)b * TQv * HD;
    const short* Bk = K + (size_t)b * TKv * HD;
    f32x4 acc[4][4] = {};
    gemm128_core<false>(Aq + (size_t)tile_m * HD, HD, Bk + (size_t)tile_n * HD, HD, HD,
                        As, Bs, acc, tid);
    short* Sb = S + (size_t)b * TQv * TKv;
    const unsigned long long* Mb = Mbits + (size_t)b * TQv * (TKv / 64);
    float* Lb = L + (size_t)b * TQv;
    int word = (tile_n >> 6) + (wave >> 1);
    int l15 = lane & 15;
    int col0 = tile_n + (wave >> 1) * 64 + l15;
#pragma unroll
    for (int mf = 0; mf < 4; ++mf)
#pragma unroll
        for (int r = 0; r < 4; ++r) {
            int gm = EGM(mf, r);
            unsigned long long bits = Mb[(size_t)gm * (TKv / 64) + word];
            float rs = 0.f;
#pragma unroll
            for (int nf = 0; nf < 4; ++nf) {
                float s = acc[mf][nf][r] * 0.03125f;
                float pv = ((bits >> (nf * 16 + l15)) & 1ULL)
                               ? exp2f((s - 4.0f) * 1.44269504f) : 0.f;
                rs += pv;
                union { _Float16 h; short sh; } cv;
                cv.h = (_Float16)pv;
                Sb[(size_t)gm * TKv + col0 + nf * 16] = cv.sh;
            }
            for (int sh = 1; sh < 16; sh <<= 1) rs += __shfl_xor(rs, sh);
            if (l15 == 0) atomicAdd(&Lb[gm], rs);
        }
}

// ---- pv: O = (P' . Vt^T) / L, fp16 MFMA, fp32 out ----
__global__ __launch_bounds__(256, 3) void pv_kernel(const short* __restrict__ P,
                                                    const short* __restrict__ Vt,
                                                    const float* __restrict__ L,
                                                    float* __restrict__ Out) {
    __shared__ short As[128 * 64];
    __shared__ short Bs[128 * 64];
    int tid = threadIdx.x;
    int wave = tid >> 6, lane = tid & 63;
    int id = blockIdx.x;
    int b = id & 7;                    // batch -> XCD binding
    int i = id >> 3;
    int n_t = i & 7;                   // over HD
    int m_t = i >> 3;                  // over TQv
    int tile_m = m_t * 128;
    int tile_n = n_t * 128;
    const short* Ap = P + (size_t)b * TQv * TKv;
    const short* Bv = Vt + (size_t)b * HD * TKv;
    const float* Lb = L + (size_t)b * TQv;
    f32x4 acc[4][4] = {};
    gemm128_core<true>(Ap + (size_t)tile_m * TKv, TKv, Bv + (size_t)tile_n * TKv, TKv, TKv,
                       As, Bs, acc, tid);
    float* Ob = Out + (size_t)b * TQv * HD;
#pragma unroll
    for (int mf = 0; mf < 4; ++mf)
#pragma unroll
        for (int r = 0; r < 4; ++r) {
            int gm = EGM(mf, r);
            float l = Lb[gm];
            float inv = (l > 0.f) ? 1.f / l : 0.f;
#pragma unroll
            for (int nf = 0; nf < 4; ++nf)
                Ob[(size_t)gm * HD + EGN(nf)] = acc[mf][nf][r] * inv;
        }
}

extern "C" void kernel_launch(void* const* d_in, const int* in_sizes, int n_in,
                              void* d_out, int out_size, void* d_ws, size_t ws_size,
                              hipStream_t stream) {
    const float* query = (const float*)d_in[0];
    const float* enc   = (const float*)d_in[1];
    const int*   mask  = (const int*)d_in[2];
    const float* Wq    = (const float*)d_in[3];
    const float* bq    = (const float*)d_in[4];
    const float* Wk    = (const float*)d_in[5];
    const float* bk    = (const float*)d_in[6];
    const float* Wv    = (const float*)d_in[7];
    const float* bv    = (const float*)d_in[8];
    float* out = (float*)d_out;

    // workspace layout (bytes); total 174,063,616
    //   [0, 6.29MB): Wtq/Wtk/Wtv bf16 (wtrans -> projqk/projv), then reused as
    //     Mbits [0,4MB) + L [4MB,4MB+64KB) once the Wt copies are dead.
    //   S (fp16 P', 67MB) aliases Xq+Xe (dead after projqk/projv).
    char* ws = (char*)d_ws;
    short* Wt  = (short*)(ws);
    unsigned long long* Mbits = (unsigned long long*)(ws);
    float* L   = (float*)(ws + 4194304);
    short* Xq  = (short*)(ws + 6291456);
    short* Xe  = (short*)(ws + 39845888);
    short* S   = (short*)(ws + 6291456);       // aliases Xq,Xe
    short* Qb  = (short*)(ws + 73400320);
    short* Kb  = (short*)(ws + 106954752);
    short* Vt  = (short*)(ws + 140509184);
    (void)in_sizes; (void)n_in; (void)out_size; (void)ws_size;

    convert_kernel<<<dim3(8192, 2), 256, 0, stream>>>(query, enc, Xq, Xe);
    wtrans_kernel<<<dim3(32, 32, 3), dim3(32, 8), 0, stream>>>(Wq, Wk, Wv, Wt);
    projqk_kernel<<<dim3(1024, 1, 2), 256, 0, stream>>>(Xq, Xe, Wt, bq, bk, Qb, Kb);
    projv_kernel<<<dim3(1024), 256, 0, stream>>>(Xe, Wt + (size_t)2 * HD * FD, bv, Vt);
    maskbits_kernel<<<dim3(2048), 256, 0, stream>>>(mask, Mbits, L);
    score_kernel<<<dim3(2048), 256, 0, stream>>>(Qb, Kb, Mbits, S, L);
    pv_kernel<<<dim3(1024), 256, 0, stream>>>(S, Vt, L, out);
}

// Round 5
// 590.804 us; speedup vs baseline: 1.3459x; 1.0578x over previous
//
#include <hip/hip_runtime.h>

#define NB 8
#define TQv 2048
#define TKv 2048
#define FD 1024
#define HD 1024

typedef __attribute__((ext_vector_type(8))) short short8;
typedef __attribute__((ext_vector_type(8))) _Float16 half8;
typedef __attribute__((ext_vector_type(4))) float f32x4;

// round-to-nearest-even fp32 -> bf16 (finite inputs only)
__device__ __forceinline__ short f2bf(float f) {
    union { float f; unsigned u; } v; v.f = f;
    unsigned r = v.u + 0x7FFFu + ((v.u >> 16) & 1u);
    return (short)(r >> 16);
}

__device__ __forceinline__ half8 as_h8(short8 v) {
    union { short8 s; half8 h; } u; u.s = v; return u.h;
}

// async 16B global -> LDS (global_load_lds_dwordx4); LDS dest = wave-uniform base + lane*16
__device__ __forceinline__ void async16(const short* g, short* l) {
    __builtin_amdgcn_global_load_lds(
        (const __attribute__((address_space(1))) unsigned int*)g,
        (__attribute__((address_space(3))) unsigned int*)l, 16, 0, 0);
}

// 32-bit LDS byte offset of a generic pointer into __shared__
__device__ __forceinline__ unsigned lds_off(void* p) {
    return (unsigned)(unsigned long long)(__attribute__((address_space(3))) char*)p;
}

#define BAR  __builtin_amdgcn_s_barrier()
#define SP1  __builtin_amdgcn_s_setprio(1)
#define SP0  __builtin_amdgcn_s_setprio(0)
#define SCB  __builtin_amdgcn_sched_barrier(0)
#define VMCNT(N) asm volatile("s_waitcnt vmcnt(" #N ")" ::: "memory")
#define LGKC(N)  asm volatile("s_waitcnt lgkmcnt(" #N ")" ::: "memory")

// ds_read_b128 as INLINE ASM: opaque to the memory legalizer, so hipcc cannot insert
// conservative s_waitcnt vmcnt(0) before LDS reads that might alias in-flight
// global_load_lds writes (the round-1/2 17%-MfmaUtil failure mode). Completion is
// enforced manually: counted LGKC + sched_barrier(0) (rule #18).
#define DSR(dst, addr, OFS) \
    asm volatile("ds_read_b128 %0, %1 offset:" OFS : "=v"(dst) : "v"(addr))

// ============ 256x256 8-phase GEMM core (T2+T3+T4+T5, asm-ds_read) ============
// NT: C[m][n] = sum_k A[m][k]*B[n][k]. 512 thr = 8 waves (2M x 4N); wave C = 128x64
// = acc[8][4] f32x4; 16x16x32 MFMA; BK=64; K-tiles double-buffered in 128 KiB LDS:
// buf{0,1} x [ A 256x64 (2 halves of 128 rows) | B 256x64 ] bf16, XOR swizzle
// (verified rounds 1-2: passed correctness, SQ_LDS_BANK_CONFLICT == 0):
//   element (r,k) of a half -> 16B block L = 8r + ((k>>3)^(r&7)), byte (k&7)*2;
//   stage call = 8KB = 64 rows, lane covers row lr=l>>3, src chunk kc=(l&7)^lr.
// Phase reads (quadrant order (0,0),(1,0),(0,1),(1,1)) with register reuse:
//   P1: aQ0 (8) + bQ0 (4) [lgkmcnt(8) pace]; P2: aQ1 (8); P3: bQ1 (4); P4: none.
// Stage ledger (1 half-tile = 2 loads per phase; tiles a=2i->buf0, b=a+1->buf1):
//   P1: b.B0   P2: b.B1   P3: a2.A0  P4: a2.A1 + VMCNT(4)
//   P5: a2.B0  P6: a2.B1  P7: b2.A0  P8: b2.A1 + VMCNT(4)
// WAR: every stage targets a region whose last reads drained >=1 closing barrier
// earlier (A halves read P1+P2 -> free P3; B halves read P1+P3 / P5+P7 -> free P4/P8).
// RAW: VMCNT(4)@P4 leaves only P3/P4 stages in flight => tile b fully landed before
// P5; VMCNT(4)@P8 leaves P7/P8 => tile a2 landed before next P1. Last iter: VMCNT(0)@P4.
#define RD_ALO(BF) { DSR(aQ0[0][0], adA0[BF], "0");    DSR(aQ0[0][1], adA1[BF], "0"); \
                     DSR(aQ0[1][0], adA0[BF], "2048"); DSR(aQ0[1][1], adA1[BF], "2048"); \
                     DSR(aQ0[2][0], adA0[BF], "4096"); DSR(aQ0[2][1], adA1[BF], "4096"); \
                     DSR(aQ0[3][0], adA0[BF], "6144"); DSR(aQ0[3][1], adA1[BF], "6144"); }
#define RD_AHI(BF) { DSR(aQ1[0][0], adA0[BF], "8192");  DSR(aQ1[0][1], adA1[BF], "8192"); \
                     DSR(aQ1[1][0], adA0[BF], "10240"); DSR(aQ1[1][1], adA1[BF], "10240"); \
                     DSR(aQ1[2][0], adA0[BF], "12288"); DSR(aQ1[2][1], adA1[BF], "12288"); \
                     DSR(aQ1[3][0], adA0[BF], "14336"); DSR(aQ1[3][1], adA1[BF], "14336"); }
#define RD_BLO(BF) { DSR(bQ0[0][0], adB0[BF], "0");    DSR(bQ0[0][1], adB1[BF], "0"); \
                     DSR(bQ0[1][0], adB0[BF], "2048"); DSR(bQ0[1][1], adB1[BF], "2048"); }
#define RD_BHI(BF) { DSR(bQ1[0][0], adB0[BF], "4096"); DSR(bQ1[0][1], adB1[BF], "4096"); \
                     DSR(bQ1[1][0], adB0[BF], "6144"); DSR(bQ1[1][1], adB1[BF], "6144"); }

#define QMFMA(AQ, BQ, MO, NO) { \
    _Pragma("unroll") for (int ks = 0; ks < 2; ++ks) \
    _Pragma("unroll") for (int f = 0; f < 4; ++f) \
    _Pragma("unroll") for (int n = 0; n < 2; ++n) { \
        if constexpr (F16) \
            acc[(MO)+f][(NO)+n] = __builtin_amdgcn_mfma_f32_16x16x32_f16( \
                as_h8(AQ[f][ks]), as_h8(BQ[n][ks]), acc[(MO)+f][(NO)+n], 0, 0, 0); \
        else \
            acc[(MO)+f][(NO)+n] = __builtin_amdgcn_mfma_f32_16x16x32_bf16( \
                AQ[f][ks], BQ[n][ks], acc[(MO)+f][(NO)+n], 0, 0, 0); } }

// stage one half-tile (2 x async16); REL/tofs in shorts (k-units)
#define STG_A(BF, H, REL) { \
    async16(gaBase + sH[2*(H)+0] + tofs + (REL), lbase + (BF)*32768 + (H)*8192); \
    async16(gaBase + sH[2*(H)+1] + tofs + (REL), lbase + (BF)*32768 + (H)*8192 + 4096); }
#define STG_B(BF, H, REL) { \
    async16(gbBase + sH[2*(H)+0] + tofs + (REL), lbase + (BF)*32768 + 16384 + (H)*8192); \
    async16(gbBase + sH[2*(H)+1] + tofs + (REL), lbase + (BF)*32768 + 16384 + (H)*8192 + 4096); }

template <bool F16>
__device__ __forceinline__ void gemm256_core(const short* __restrict__ A,
                                             const short* __restrict__ B,
                                             int ld, int K, char* smem,
                                             f32x4 acc[8][4], int tid) {
    const int wid = tid >> 6, lane = tid & 63;
    const int wm = wid >> 2, wn = wid & 3;
    const int l15 = lane & 15;

    // staging: per-thread global base + SGPR row-window offsets
    const int kc8 = ((lane & 7) ^ (lane >> 3)) * 8;
    const short* gaBase = A + (size_t)(wid * 8 + (lane >> 3)) * ld + kc8;
    const short* gbBase = B + (size_t)(wid * 8 + (lane >> 3)) * ld + kc8;
    size_t sH[4];
#pragma unroll
    for (int k = 0; k < 4; ++k) sH[k] = (size_t)k * 64 * ld;
    short* lbase = (short*)smem + wid * 512;

    // loop-invariant 32-bit LDS read addresses (ks0/ks1 swizzled chunk, per buf)
    const int o0 = (((lane >> 4)    ) ^ (lane & 7)) * 16;
    const int o1 = (((lane >> 4) + 4) ^ (lane & 7)) * 16;
    unsigned aB_ = lds_off(smem) + wm * 16384 + l15 * 128;
    unsigned bB_ = lds_off(smem) + 32768 + (wn >> 1) * 16384 + (wn & 1) * 8192 + l15 * 128;
    unsigned adA0[2] = { aB_ + o0, aB_ + o0 + 65536u };
    unsigned adA1[2] = { aB_ + o1, aB_ + o1 + 65536u };
    unsigned adB0[2] = { bB_ + o0, bB_ + o0 + 65536u };
    unsigned adB1[2] = { bB_ + o1, bB_ + o1 + 65536u };

    int tofs = 0;
    // prologue: tile0 full -> buf0, tile1 A halves -> buf1
    STG_A(0, 0, 0); STG_A(0, 1, 0); STG_B(0, 0, 0); STG_B(0, 1, 0);
    STG_A(1, 0, 64); STG_A(1, 1, 64);
    SCB; VMCNT(4); BAR; SCB;

    short8 aQ0[4][2], aQ1[4][2], bQ0[2][2], bQ1[2][2];
    const int niter = K >> 7;
    for (int it = 0; it < niter; ++it) {
        const bool nl = (it != niter - 1);
        // P1
        RD_ALO(0); RD_BLO(0);
        STG_B(1, 0, 64);
        SCB; LGKC(8); BAR; LGKC(0); SCB;
        SP1; QMFMA(aQ0, bQ0, 0, 0); SP0; SCB; BAR; SCB;
        // P2
        RD_AHI(0);
        STG_B(1, 1, 64);
        SCB; BAR; LGKC(0); SCB;
        SP1; QMFMA(aQ1, bQ0, 4, 0); SP0; SCB; BAR; SCB;
        // P3
        RD_BHI(0);
        if (nl) STG_A(0, 0, 128);
        SCB; BAR; LGKC(0); SCB;
        SP1; QMFMA(aQ0, bQ1, 0, 2); SP0; SCB; BAR; SCB;
        // P4
        if (nl) { STG_A(0, 1, 128); SCB; VMCNT(4); } else { SCB; VMCNT(0); }
        BAR;
        SP1; QMFMA(aQ1, bQ1, 4, 2); SP0; SCB; BAR; SCB;
        // P5
        RD_ALO(1); RD_BLO(1);
        if (nl) STG_B(0, 0, 128);
        SCB; LGKC(8); BAR; LGKC(0); SCB;
        SP1; QMFMA(aQ0, bQ0, 0, 0); SP0; SCB; BAR; SCB;
        // P6
        RD_AHI(1);
        if (nl) STG_B(0, 1, 128);
        SCB; BAR; LGKC(0); SCB;
        SP1; QMFMA(aQ1, bQ0, 4, 0); SP0; SCB; BAR; SCB;
        // P7
        RD_BHI(1);
        if (nl) STG_A(1, 0, 192);
        SCB; BAR; LGKC(0); SCB;
        SP1; QMFMA(aQ0, bQ1, 0, 2); SP0; SCB; BAR; SCB;
        // P8
        if (nl) { STG_A(1, 1, 192); SCB; VMCNT(4); }
        BAR;
        SP1; QMFMA(aQ1, bQ1, 4, 2); SP0; SCB; BAR; SCB;
        tofs += 128;
    }
}

// C/D layout per 16x16x32 frag (m89/m91): col = lane&15, row = 4*(lane>>4) + r
// global: row = tile_m + wm*128 + m*16 + 4*(lane>>4) + r ; col = tile_n + wn*64 + n*16 + (lane&15)

// ---- fp32 -> bf16 pre-pass for query & encoder_states ----
__global__ __launch_bounds__(256) void convert_kernel(const float* __restrict__ q,
                                                      const float* __restrict__ e,
                                                      short* __restrict__ xq,
                                                      short* __restrict__ xe) {
    size_t i = (size_t)blockIdx.x * 256 + threadIdx.x;
    const float* src = blockIdx.y ? e : q;
    short* dst = blockIdx.y ? xe : xq;
    float4 a = ((const float4*)src)[2 * i];
    float4 b = ((const float4*)src)[2 * i + 1];
    short8 v;
    v[0] = f2bf(a.x); v[1] = f2bf(a.y); v[2] = f2bf(a.z); v[3] = f2bf(a.w);
    v[4] = f2bf(b.x); v[5] = f2bf(b.y); v[6] = f2bf(b.z); v[7] = f2bf(b.w);
    ((short8*)dst)[i] = v;
}

// ---- W[F][H] fp32 -> Wt[H][F] bf16, z picks Wq/Wk/Wv ----
__global__ __launch_bounds__(256) void wtrans_kernel(const float* __restrict__ Wq,
                                                     const float* __restrict__ Wk,
                                                     const float* __restrict__ Wv,
                                                     short* __restrict__ Wt) {
    __shared__ float tile[32][33];
    const float* W = (blockIdx.z == 0) ? Wq : (blockIdx.z == 1) ? Wk : Wv;
    short* dst = Wt + (size_t)blockIdx.z * HD * FD;
    int h0 = blockIdx.x * 32, f0 = blockIdx.y * 32;
    int tx = threadIdx.x, ty = threadIdx.y;
    for (int j = ty; j < 32; j += 8)
        tile[j][tx] = W[(size_t)(f0 + j) * HD + h0 + tx];
    __syncthreads();
    for (int j = ty; j < 32; j += 8)
        dst[(size_t)(h0 + j) * FD + f0 + tx] = f2bf(tile[tx][j]);
}

// ---- Q/K projections: 256x256 tiles over [16384 x 1024] ----
__global__ __launch_bounds__(512, 2) void projqk_kernel(const short* __restrict__ Xq,
                                                        const short* __restrict__ Xe,
                                                        const short* __restrict__ Wt3,
                                                        const float* __restrict__ bq,
                                                        const float* __restrict__ bk,
                                                        short* __restrict__ Q,
                                                        short* __restrict__ K) {
    extern __shared__ char smem[];
    int tid = threadIdx.x;
    int p = blockIdx.z;
    const short* X = p ? Xe : Xq;
    const short* Wt = Wt3 + (size_t)p * HD * FD;
    const float* bias = p ? bk : bq;
    short* O = p ? K : Q;
    int bid = blockIdx.x;                   // XCD swizzle: m-groups bound to XCDs
    int xcd = bid & 7, idx = bid >> 3;
    int n_t = idx & 3, m_t = (idx >> 2) * 8 + xcd;
    int tile_m = m_t * 256, tile_n = n_t * 256;
    f32x4 acc[8][4] = {};
    gemm256_core<false>(X + (size_t)tile_m * FD, Wt + (size_t)tile_n * FD, FD, FD, smem, acc, tid);
    int wid = tid >> 6, lane = tid & 63;
    int wm = wid >> 2, wn = wid & 3;
    int row0 = tile_m + wm * 128 + ((lane >> 4) << 2);
    int col0 = tile_n + wn * 64 + (lane & 15);
#pragma unroll
    for (int n = 0; n < 4; ++n) {
        int gn = col0 + n * 16;
        float bv_ = bias[gn];
#pragma unroll
        for (int m = 0; m < 8; ++m)
#pragma unroll
            for (int r = 0; r < 4; ++r)
                O[(size_t)(row0 + m * 16 + r) * HD + gn] = f2bf(acc[m][n][r] + bv_);
    }
}

// ---- V projection, transposed natively: Vt[b][h][t] = Wtv[h,:].Xe[b,t,:] + bv[h], fp16 out ----
__global__ __launch_bounds__(512, 2) void projv_kernel(const short* __restrict__ Xe,
                                                       const short* __restrict__ Wtv,
                                                       const float* __restrict__ bv,
                                                       short* __restrict__ Vt) {
    extern __shared__ char smem[];
    int tid = threadIdx.x;
    int bid = blockIdx.x;
    int b = bid & 7, i = bid >> 3;          // batch -> XCD binding
    int m_t = i & 3, n_t = i >> 2;          // m over HD (4), n over TKv (8)
    int tile_m = m_t * 256, tile_n = n_t * 256;
    const short* Xb = Xe + (size_t)b * TKv * FD;
    f32x4 acc[8][4] = {};
    gemm256_core<false>(Wtv + (size_t)tile_m * FD, Xb + (size_t)tile_n * FD, FD, FD, smem, acc, tid);
    short* Ob = Vt + (size_t)b * HD * TKv;
    int wid = tid >> 6, lane = tid & 63;
    int wm = wid >> 2, wn = wid & 3;
    int row0 = tile_m + wm * 128 + ((lane >> 4) << 2);
    int col0 = tile_n + wn * 64 + (lane & 15);
#pragma unroll
    for (int m = 0; m < 8; ++m)
#pragma unroll
        for (int r = 0; r < 4; ++r) {
            int gm = row0 + m * 16 + r;     // h
            float bv_ = bv[gm];
#pragma unroll
            for (int n = 0; n < 4; ++n) {
                union { _Float16 h; short s; } cv;
                cv.h = (_Float16)(acc[m][n][r] + bv_);
                Ob[(size_t)gm * TKv + col0 + n * 16] = cv.s;
            }
        }
}

// ---- mask int32 -> bitmask u64 (ballot), + zero row-sum array L ----
__global__ __launch_bounds__(256) void maskbits_kernel(const int* __restrict__ mask,
                                                       unsigned long long* __restrict__ Mbits,
                                                       float* __restrict__ L) {
    int tid = threadIdx.x;
    int lane = tid & 63;
    if (blockIdx.x < 64) L[blockIdx.x * 256 + tid] = 0.f;
    const int NW = NB * TQv * (TKv / 64);
    int stride = gridDim.x * 4;
    for (int w = blockIdx.x * 4 + (tid >> 6); w < NW; w += stride) {
        int v = mask[(size_t)w * 64 + lane];
        unsigned long long bal = __ballot(v != 0);
        if (lane == 0) Mbits[w] = bal;
    }
}

// ---- score: P' = mask ? exp(QK/32 - 4) : 0 (fp16), row partials -> atomicAdd L ----
__global__ __launch_bounds__(512, 2) void score_kernel(const short* __restrict__ Q,
                                                       const short* __restrict__ K,
                                                       const unsigned long long* __restrict__ Mbits,
                                                       short* __restrict__ S,
                                                       float* __restrict__ L) {
    extern __shared__ char smem[];
    int tid = threadIdx.x;
    int bid = blockIdx.x;
    int b = bid & 7, i = bid >> 3;          // batch -> XCD binding
    int n_t = i & 7, m_t = i >> 3;
    int tile_m = m_t * 256, tile_n = n_t * 256;
    const short* Aq = Q + (size_t)b * TQv * HD;
    const short* Bk = K + (size_t)b * TKv * HD;
    f32x4 acc[8][4] = {};
    gemm256_core<false>(Aq + (size_t)tile_m * HD, Bk + (size_t)tile_n * HD, HD, HD, smem, acc, tid);
    short* Sb = S + (size_t)b * TQv * TKv;
    const unsigned long long* Mb = Mbits + (size_t)b * TQv * (TKv / 64);
    float* Lb = L + (size_t)b * TQv;
    int wid = tid >> 6, lane = tid & 63;
    int wm = wid >> 2, wn = wid & 3;
    int l15 = lane & 15;
    int row0 = tile_m + wm * 128 + ((lane >> 4) << 2);
    int col0 = tile_n + wn * 64 + l15;
    int word = (tile_n + wn * 64) >> 6;
#pragma unroll
    for (int m = 0; m < 8; ++m)
#pragma unroll
        for (int r = 0; r < 4; ++r) {
            int gm = row0 + m * 16 + r;
            unsigned long long bits = Mb[(size_t)gm * (TKv / 64) + word];
            float rs = 0.f;
#pragma unroll
            for (int n = 0; n < 4; ++n) {
                float s = acc[m][n][r] * 0.03125f;
                float pv = ((bits >> (n * 16 + l15)) & 1ULL)
                               ? exp2f((s - 4.0f) * 1.44269504f) : 0.f;
                rs += pv;
                union { _Float16 h; short sh; } cv;
                cv.h = (_Float16)pv;
                Sb[(size_t)gm * TKv + col0 + n * 16] = cv.sh;
            }
            for (int sh = 1; sh < 16; sh <<= 1) rs += __shfl_xor(rs, sh);
            if (l15 == 0) atomicAdd(&Lb[gm], rs);
        }
}

// ---- pv: O = (P' . Vt^T) / L, fp16 MFMA, fp32 out ----
__global__ __launch_bounds__(512, 2) void pv_kernel(const short* __restrict__ P,
                                                    const short* __restrict__ Vt,
                                                    const float* __restrict__ L,
                                                    float* __restrict__ Out) {
    extern __shared__ char smem[];
    int tid = threadIdx.x;
    int bid = blockIdx.x;
    int b = bid & 7, i = bid >> 3;          // batch -> XCD binding
    int n_t = i & 3, m_t = i >> 2;          // n over HD (4), m over TQv (8)
    int tile_m = m_t * 256, tile_n = n_t * 256;
    const short* Ap = P + (size_t)b * TQv * TKv;
    const short* Bv = Vt + (size_t)b * HD * TKv;
    const float* Lb = L + (size_t)b * TQv;
    f32x4 acc[8][4] = {};
    gemm256_core<true>(Ap + (size_t)tile_m * TKv, Bv + (size_t)tile_n * TKv, TKv, TKv, smem, acc, tid);
    float* Ob = Out + (size_t)b * TQv * HD;
    int wid = tid >> 6, lane = tid & 63;
    int wm = wid >> 2, wn = wid & 3;
    int row0 = tile_m + wm * 128 + ((lane >> 4) << 2);
    int col0 = tile_n + wn * 64 + (lane & 15);
#pragma unroll
    for (int m = 0; m < 8; ++m)
#pragma unroll
        for (int r = 0; r < 4; ++r) {
            int gm = row0 + m * 16 + r;
            float l = Lb[gm];
            float inv = (l > 0.f) ? 1.f / l : 0.f;
#pragma unroll
            for (int n = 0; n < 4; ++n)
                Ob[(size_t)gm * HD + col0 + n * 16] = acc[m][n][r] * inv;
        }
}

extern "C" void kernel_launch(void* const* d_in, const int* in_sizes, int n_in,
                              void* d_out, int out_size, void* d_ws, size_t ws_size,
                              hipStream_t stream) {
    const float* query = (const float*)d_in[0];
    const float* enc   = (const float*)d_in[1];
    const int*   mask  = (const int*)d_in[2];
    const float* Wq    = (const float*)d_in[3];
    const float* bq    = (const float*)d_in[4];
    const float* Wk    = (const float*)d_in[5];
    const float* bk    = (const float*)d_in[6];
    const float* Wv    = (const float*)d_in[7];
    const float* bv    = (const float*)d_in[8];
    float* out = (float*)d_out;

    // workspace layout (bytes); total 174,063,616
    //   [0, 6.29MB): Wtq/Wtk/Wtv bf16 (wtrans -> projqk/projv), then reused as
    //     Mbits [0,4MB) + L [4MB,4MB+64KB) once the Wt copies are dead.
    //   S (fp16 P', 67MB) aliases Xq+Xe (dead after projqk/projv).
    char* ws = (char*)d_ws;
    short* Wt  = (short*)(ws);
    unsigned long long* Mbits = (unsigned long long*)(ws);
    float* L   = (float*)(ws + 4194304);
    short* Xq  = (short*)(ws + 6291456);
    short* Xe  = (short*)(ws + 39845888);
    short* S   = (short*)(ws + 6291456);       // aliases Xq,Xe
    short* Qb  = (short*)(ws + 73400320);
    short* Kb  = (short*)(ws + 106954752);
    short* Vt  = (short*)(ws + 140509184);
    (void)in_sizes; (void)n_in; (void)out_size; (void)ws_size;

    // 128 KiB dynamic LDS opt-in (one-time; not a stream op, graph-capture safe)
    static bool inited = false;
    if (!inited) {
        hipFuncSetAttribute((const void*)projqk_kernel, hipFuncAttributeMaxDynamicSharedMemorySize, 131072);
        hipFuncSetAttribute((const void*)projv_kernel,  hipFuncAttributeMaxDynamicSharedMemorySize, 131072);
        hipFuncSetAttribute((const void*)score_kernel,  hipFuncAttributeMaxDynamicSharedMemorySize, 131072);
        hipFuncSetAttribute((const void*)pv_kernel,     hipFuncAttributeMaxDynamicSharedMemorySize, 131072);
        inited = true;
    }

    convert_kernel<<<dim3(8192, 2), 256, 0, stream>>>(query, enc, Xq, Xe);
    wtrans_kernel<<<dim3(32, 32, 3), dim3(32, 8), 0, stream>>>(Wq, Wk, Wv, Wt);
    projqk_kernel<<<dim3(256, 1, 2), 512, 131072, stream>>>(Xq, Xe, Wt, bq, bk, Qb, Kb);
    projv_kernel<<<dim3(256), 512, 131072, stream>>>(Xe, Wt + (size_t)2 * HD * FD, bv, Vt);
    maskbits_kernel<<<dim3(2048), 256, 0, stream>>>(mask, Mbits, L);
    score_kernel<<<dim3(512), 512, 131072, stream>>>(Qb, Kb, Mbits, S, L);
    pv_kernel<<<dim3(256), 512, 131072, stream>>>(S, Vt, L, out);
}

// Round 6
// 578.446 us; speedup vs baseline: 1.3746x; 1.0214x over previous
//
#include <hip/hip_runtime.h>

#define NB 8
#define TQv 2048
#define TKv 2048
#define FD 1024
#define HD 1024

typedef __attribute__((ext_vector_type(8))) short short8;
typedef __attribute__((ext_vector_type(8))) _Float16 half8;
typedef __attribute__((ext_vector_type(4))) float f32x4;

// round-to-nearest-even fp32 -> bf16 (finite inputs only)
__device__ __forceinline__ short f2bf(float f) {
    union { float f; unsigned u; } v; v.f = f;
    unsigned r = v.u + 0x7FFFu + ((v.u >> 16) & 1u);
    return (short)(r >> 16);
}

__device__ __forceinline__ half8 as_h8(short8 v) {
    union { short8 s; half8 h; } u; u.s = v; return u.h;
}

// async 16B global -> LDS (global_load_lds_dwordx4); LDS dest = wave-uniform base + lane*16
__device__ __forceinline__ void async16(const short* g, short* l) {
    __builtin_amdgcn_global_load_lds(
        (const __attribute__((address_space(1))) unsigned int*)g,
        (__attribute__((address_space(3))) unsigned int*)l, 16, 0, 0);
}

// 32-bit LDS byte offset of a generic pointer into __shared__
__device__ __forceinline__ unsigned lds_off(void* p) {
    return (unsigned)(unsigned long long)(__attribute__((address_space(3))) char*)p;
}

#define BAR  __builtin_amdgcn_s_barrier()
#define SP1  __builtin_amdgcn_s_setprio(1)
#define SP0  __builtin_amdgcn_s_setprio(0)
#define SCB  __builtin_amdgcn_sched_barrier(0)
#define VMCNT(N) asm volatile("s_waitcnt vmcnt(" #N ")" ::: "memory")
#define LGKC(N)  asm volatile("s_waitcnt lgkmcnt(" #N ")" ::: "memory")

// ds_read_b128 as INLINE ASM: opaque to the memory legalizer, so hipcc cannot insert
// conservative s_waitcnt vmcnt(0) before LDS reads that might alias in-flight
// global_load_lds writes (the round-1/2 17%-MfmaUtil failure mode). Completion is
// enforced manually: counted LGKC + sched_barrier(0) (rule #18).
#define DSR(dst, addr, OFS) \
    asm volatile("ds_read_b128 %0, %1 offset:" OFS : "=v"(dst) : "v"(addr))

// ============ 256x256 8-phase GEMM core (T2+T3+T4+T5, asm-ds_read) ============
// NT: C[m][n] = sum_k A[m][k]*B[n][k]. 512 thr = 8 waves (2M x 4N); wave C = 128x64
// = acc[8][4] f32x4; 16x16x32 MFMA; BK=64; K-tiles double-buffered in 128 KiB LDS:
// buf{0,1} x [ A 256x64 (2 halves of 128 rows) | B 256x64 ] bf16, XOR swizzle
// (verified: passed correctness, SQ_LDS_BANK_CONFLICT == 0):
//   element (r,k) of a half -> 16B block L = 8r + ((k>>3)^(r&7)), byte (k&7)*2;
//   stage call = 8KB = 64 rows, lane covers row lr=l>>3, src chunk kc=(l&7)^lr.
// Phase reads (quadrant order (0,0),(1,0),(0,1),(1,1)) with register reuse:
//   P1: aQ0 (8) + bQ0 (4) [lgkmcnt(8) pace]; P2: aQ1 (8); P3: bQ1 (4); P4: none.
// Stage ledger (1 half-tile = 2 loads per phase; tiles a=2i->buf0, b=a+1->buf1):
//   P1: b.B0   P2: b.B1   P3: a2.A0  P4: a2.A1 + VMCNT(4)
//   P5: a2.B0  P6: a2.B1  P7: b2.A0  P8: b2.A1 + VMCNT(4)
// WAR: every stage targets a region whose last reads drained >=1 closing barrier
// earlier.  RAW: VMCNT(4)@P4/P8 leaves only the 2 newest half-tiles in flight =>
// the tile computed next is landed.  Last iter: VMCNT(0)@P4.
#define RD_ALO(BF) { DSR(aQ0[0][0], adA0[BF], "0");    DSR(aQ0[0][1], adA1[BF], "0"); \
                     DSR(aQ0[1][0], adA0[BF], "2048"); DSR(aQ0[1][1], adA1[BF], "2048"); \
                     DSR(aQ0[2][0], adA0[BF], "4096"); DSR(aQ0[2][1], adA1[BF], "4096"); \
                     DSR(aQ0[3][0], adA0[BF], "6144"); DSR(aQ0[3][1], adA1[BF], "6144"); }
#define RD_AHI(BF) { DSR(aQ1[0][0], adA0[BF], "8192");  DSR(aQ1[0][1], adA1[BF], "8192"); \
                     DSR(aQ1[1][0], adA0[BF], "10240"); DSR(aQ1[1][1], adA1[BF], "10240"); \
                     DSR(aQ1[2][0], adA0[BF], "12288"); DSR(aQ1[2][1], adA1[BF], "12288"); \
                     DSR(aQ1[3][0], adA0[BF], "14336"); DSR(aQ1[3][1], adA1[BF], "14336"); }
#define RD_BLO(BF) { DSR(bQ0[0][0], adB0[BF], "0");    DSR(bQ0[0][1], adB1[BF], "0"); \
                     DSR(bQ0[1][0], adB0[BF], "2048"); DSR(bQ0[1][1], adB1[BF], "2048"); }
#define RD_BHI(BF) { DSR(bQ1[0][0], adB0[BF], "4096"); DSR(bQ1[0][1], adB1[BF], "4096"); \
                     DSR(bQ1[1][0], adB0[BF], "6144"); DSR(bQ1[1][1], adB1[BF], "6144"); }

#define QMFMA(AQ, BQ, MO, NO) { \
    _Pragma("unroll") for (int ks = 0; ks < 2; ++ks) \
    _Pragma("unroll") for (int f = 0; f < 4; ++f) \
    _Pragma("unroll") for (int n = 0; n < 2; ++n) { \
        if constexpr (F16) \
            acc[(MO)+f][(NO)+n] = __builtin_amdgcn_mfma_f32_16x16x32_f16( \
                as_h8(AQ[f][ks]), as_h8(BQ[n][ks]), acc[(MO)+f][(NO)+n], 0, 0, 0); \
        else \
            acc[(MO)+f][(NO)+n] = __builtin_amdgcn_mfma_f32_16x16x32_bf16( \
                AQ[f][ks], BQ[n][ks], acc[(MO)+f][(NO)+n], 0, 0, 0); } }

// stage one half-tile (2 x async16); REL/tofs in shorts (k-units)
#define STG_A(BF, H, REL) { \
    async16(gaBase + sH[2*(H)+0] + tofs + (REL), lbase + (BF)*32768 + (H)*8192); \
    async16(gaBase + sH[2*(H)+1] + tofs + (REL), lbase + (BF)*32768 + (H)*8192 + 4096); }
#define STG_B(BF, H, REL) { \
    async16(gbBase + sH[2*(H)+0] + tofs + (REL), lbase + (BF)*32768 + 16384 + (H)*8192); \
    async16(gbBase + sH[2*(H)+1] + tofs + (REL), lbase + (BF)*32768 + 16384 + (H)*8192 + 4096); }

template <bool F16>
__device__ __forceinline__ void gemm256_core(const short* __restrict__ A,
                                             const short* __restrict__ B,
                                             int ld, int K, char* smem,
                                             f32x4 acc[8][4], int tid) {
    const int wid = tid >> 6, lane = tid & 63;
    const int wm = wid >> 2, wn = wid & 3;
    const int l15 = lane & 15;

    // staging: per-thread global base + SGPR row-window offsets
    const int kc8 = ((lane & 7) ^ (lane >> 3)) * 8;
    const short* gaBase = A + (size_t)(wid * 8 + (lane >> 3)) * ld + kc8;
    const short* gbBase = B + (size_t)(wid * 8 + (lane >> 3)) * ld + kc8;
    size_t sH[4];
#pragma unroll
    for (int k = 0; k < 4; ++k) sH[k] = (size_t)k * 64 * ld;
    short* lbase = (short*)smem + wid * 512;

    // loop-invariant 32-bit LDS read addresses (ks0/ks1 swizzled chunk, per buf)
    const int o0 = (((lane >> 4)    ) ^ (lane & 7)) * 16;
    const int o1 = (((lane >> 4) + 4) ^ (lane & 7)) * 16;
    unsigned aB_ = lds_off(smem) + wm * 16384 + l15 * 128;
    unsigned bB_ = lds_off(smem) + 32768 + (wn >> 1) * 16384 + (wn & 1) * 8192 + l15 * 128;
    unsigned adA0[2] = { aB_ + o0, aB_ + o0 + 65536u };
    unsigned adA1[2] = { aB_ + o1, aB_ + o1 + 65536u };
    unsigned adB0[2] = { bB_ + o0, bB_ + o0 + 65536u };
    unsigned adB1[2] = { bB_ + o1, bB_ + o1 + 65536u };

    int tofs = 0;
    // prologue: tile0 full -> buf0, tile1 A halves -> buf1
    STG_A(0, 0, 0); STG_A(0, 1, 0); STG_B(0, 0, 0); STG_B(0, 1, 0);
    STG_A(1, 0, 64); STG_A(1, 1, 64);
    SCB; VMCNT(4); BAR; SCB;

    short8 aQ0[4][2], aQ1[4][2], bQ0[2][2], bQ1[2][2];
    const int niter = K >> 7;
    for (int it = 0; it < niter; ++it) {
        const bool nl = (it != niter - 1);
        // P1
        RD_ALO(0); RD_BLO(0);
        STG_B(1, 0, 64);
        SCB; LGKC(8); BAR; LGKC(0); SCB;
        SP1; QMFMA(aQ0, bQ0, 0, 0); SP0; SCB; BAR; SCB;
        // P2
        RD_AHI(0);
        STG_B(1, 1, 64);
        SCB; BAR; LGKC(0); SCB;
        SP1; QMFMA(aQ1, bQ0, 4, 0); SP0; SCB; BAR; SCB;
        // P3
        RD_BHI(0);
        if (nl) STG_A(0, 0, 128);
        SCB; BAR; LGKC(0); SCB;
        SP1; QMFMA(aQ0, bQ1, 0, 2); SP0; SCB; BAR; SCB;
        // P4
        if (nl) { STG_A(0, 1, 128); SCB; VMCNT(4); } else { SCB; VMCNT(0); }
        BAR;
        SP1; QMFMA(aQ1, bQ1, 4, 2); SP0; SCB; BAR; SCB;
        // P5
        RD_ALO(1); RD_BLO(1);
        if (nl) STG_B(0, 0, 128);
        SCB; LGKC(8); BAR; LGKC(0); SCB;
        SP1; QMFMA(aQ0, bQ0, 0, 0); SP0; SCB; BAR; SCB;
        // P6
        RD_AHI(1);
        if (nl) STG_B(0, 1, 128);
        SCB; BAR; LGKC(0); SCB;
        SP1; QMFMA(aQ1, bQ0, 4, 0); SP0; SCB; BAR; SCB;
        // P7
        RD_BHI(1);
        if (nl) STG_A(1, 0, 192);
        SCB; BAR; LGKC(0); SCB;
        SP1; QMFMA(aQ0, bQ1, 0, 2); SP0; SCB; BAR; SCB;
        // P8
        if (nl) { STG_A(1, 1, 192); SCB; VMCNT(4); }
        BAR;
        SP1; QMFMA(aQ1, bQ1, 4, 2); SP0; SCB; BAR; SCB;
        tofs += 128;
    }
}

// C/D layout per 16x16x32 frag (m89/m91): col = lane&15, row = 4*(lane>>4) + r
// global: row = tile_m + wm*128 + m*16 + 4*(lane>>4) + r ; col = tile_n + wn*64 + n*16 + (lane&15)

// ---- fp32 -> bf16 pre-pass for query & encoder_states ----
__global__ __launch_bounds__(256) void convert_kernel(const float* __restrict__ q,
                                                      const float* __restrict__ e,
                                                      short* __restrict__ xq,
                                                      short* __restrict__ xe) {
    size_t i = (size_t)blockIdx.x * 256 + threadIdx.x;
    const float* src = blockIdx.y ? e : q;
    short* dst = blockIdx.y ? xe : xq;
    float4 a = ((const float4*)src)[2 * i];
    float4 b = ((const float4*)src)[2 * i + 1];
    short8 v;
    v[0] = f2bf(a.x); v[1] = f2bf(a.y); v[2] = f2bf(a.z); v[3] = f2bf(a.w);
    v[4] = f2bf(b.x); v[5] = f2bf(b.y); v[6] = f2bf(b.z); v[7] = f2bf(b.w);
    ((short8*)dst)[i] = v;
}

// ---- W[F][H] fp32 -> Wt[H][F] bf16, z picks Wq/Wk/Wv ----
__global__ __launch_bounds__(256) void wtrans_kernel(const float* __restrict__ Wq,
                                                     const float* __restrict__ Wk,
                                                     const float* __restrict__ Wv,
                                                     short* __restrict__ Wt) {
    __shared__ float tile[32][33];
    const float* W = (blockIdx.z == 0) ? Wq : (blockIdx.z == 1) ? Wk : Wv;
    short* dst = Wt + (size_t)blockIdx.z * HD * FD;
    int h0 = blockIdx.x * 32, f0 = blockIdx.y * 32;
    int tx = threadIdx.x, ty = threadIdx.y;
    for (int j = ty; j < 32; j += 8)
        tile[j][tx] = W[(size_t)(f0 + j) * HD + h0 + tx];
    __syncthreads();
    for (int j = ty; j < 32; j += 8)
        dst[(size_t)(h0 + j) * FD + f0 + tx] = f2bf(tile[tx][j]);
}

// ---- Q/K projections: 256x256 tiles over [16384 x 1024] ----
__global__ __launch_bounds__(512, 2) void projqk_kernel(const short* __restrict__ Xq,
                                                        const short* __restrict__ Xe,
                                                        const short* __restrict__ Wt3,
                                                        const float* __restrict__ bq,
                                                        const float* __restrict__ bk,
                                                        short* __restrict__ Q,
                                                        short* __restrict__ K) {
    extern __shared__ char smem[];
    int tid = threadIdx.x;
    int p = blockIdx.z;
    const short* X = p ? Xe : Xq;
    const short* Wt = Wt3 + (size_t)p * HD * FD;
    const float* bias = p ? bk : bq;
    short* O = p ? K : Q;
    int bid = blockIdx.x;                   // XCD swizzle: m-groups bound to XCDs
    int xcd = bid & 7, idx = bid >> 3;
    int n_t = idx & 3, m_t = (idx >> 2) * 8 + xcd;
    int tile_m = m_t * 256, tile_n = n_t * 256;
    f32x4 acc[8][4] = {};
    gemm256_core<false>(X + (size_t)tile_m * FD, Wt + (size_t)tile_n * FD, FD, FD, smem, acc, tid);
    int wid = tid >> 6, lane = tid & 63;
    int wm = wid >> 2, wn = wid & 3;
    int row0 = tile_m + wm * 128 + ((lane >> 4) << 2);
    int col0 = tile_n + wn * 64 + (lane & 15);
#pragma unroll
    for (int n = 0; n < 4; ++n) {
        int gn = col0 + n * 16;
        float bv_ = bias[gn];
#pragma unroll
        for (int m = 0; m < 8; ++m)
#pragma unroll
            for (int r = 0; r < 4; ++r)
                O[(size_t)(row0 + m * 16 + r) * HD + gn] = f2bf(acc[m][n][r] + bv_);
    }
}

// ---- V projection, transposed natively: Vt[b][h][t] = Wtv[h,:].Xe[b,t,:] + bv[h], fp16 out ----
__global__ __launch_bounds__(512, 2) void projv_kernel(const short* __restrict__ Xe,
                                                       const short* __restrict__ Wtv,
                                                       const float* __restrict__ bv,
                                                       short* __restrict__ Vt) {
    extern __shared__ char smem[];
    int tid = threadIdx.x;
    int bid = blockIdx.x;
    int b = bid & 7, i = bid >> 3;          // batch -> XCD binding
    int m_t = i & 3, n_t = i >> 2;          // m over HD (4), n over TKv (8)
    int tile_m = m_t * 256, tile_n = n_t * 256;
    const short* Xb = Xe + (size_t)b * TKv * FD;
    f32x4 acc[8][4] = {};
    gemm256_core<false>(Wtv + (size_t)tile_m * FD, Xb + (size_t)tile_n * FD, FD, FD, smem, acc, tid);
    short* Ob = Vt + (size_t)b * HD * TKv;
    int wid = tid >> 6, lane = tid & 63;
    int wm = wid >> 2, wn = wid & 3;
    int row0 = tile_m + wm * 128 + ((lane >> 4) << 2);
    int col0 = tile_n + wn * 64 + (lane & 15);
#pragma unroll
    for (int m = 0; m < 8; ++m)
#pragma unroll
        for (int r = 0; r < 4; ++r) {
            int gm = row0 + m * 16 + r;     // h
            float bv_ = bv[gm];
#pragma unroll
            for (int n = 0; n < 4; ++n) {
                union { _Float16 h; short s; } cv;
                cv.h = (_Float16)(acc[m][n][r] + bv_);
                Ob[(size_t)gm * TKv + col0 + n * 16] = cv.s;
            }
        }
}

// ---- mask int32 -> bitmask u64 (ballot), + zero row-sum array L ----
__global__ __launch_bounds__(256) void maskbits_kernel(const int* __restrict__ mask,
                                                       unsigned long long* __restrict__ Mbits,
                                                       float* __restrict__ L) {
    int tid = threadIdx.x;
    int lane = tid & 63;
    if (blockIdx.x < 64) L[blockIdx.x * 256 + tid] = 0.f;
    const int NW = NB * TQv * (TKv / 64);
    int stride = gridDim.x * 4;
    for (int w = blockIdx.x * 4 + (tid >> 6); w < NW; w += stride) {
        int v = mask[(size_t)w * 64 + lane];
        unsigned long long bal = __ballot(v != 0);
        if (lane == 0) Mbits[w] = bal;
    }
}

// ---- score: P' = mask ? exp(QK/32 - 4) : 0 (fp16), row partials -> atomicAdd L ----
__global__ __launch_bounds__(512, 2) void score_kernel(const short* __restrict__ Q,
                                                       const short* __restrict__ K,
                                                       const unsigned long long* __restrict__ Mbits,
                                                       short* __restrict__ S,
                                                       float* __restrict__ L) {
    extern __shared__ char smem[];
    int tid = threadIdx.x;
    int bid = blockIdx.x;
    int b = bid & 7, i = bid >> 3;          // batch -> XCD binding
    int n_t = i & 7, m_t = i >> 3;
    int tile_m = m_t * 256, tile_n = n_t * 256;
    const short* Aq = Q + (size_t)b * TQv * HD;
    const short* Bk = K + (size_t)b * TKv * HD;
    f32x4 acc[8][4] = {};
    gemm256_core<false>(Aq + (size_t)tile_m * HD, Bk + (size_t)tile_n * HD, HD, HD, smem, acc, tid);
    short* Sb = S + (size_t)b * TQv * TKv;
    float* Lb = L + (size_t)b * TQv;
    int wid = tid >> 6, lane = tid & 63;
    int wm = wid >> 2, wn = wid & 3;
    int l15 = lane & 15;
    int row0 = tile_m + wm * 128 + ((lane >> 4) << 2);
    int col0 = tile_n + wn * 64 + l15;

    // ---- R6: stage this block's Mbits slab (256 rows x 4 words = 8 KB) into the
    // now-free LDS with one coalesced global_load_lds burst, instead of 32 serialized
    // dependent global loads per thread in the output loop (latency-chain killer).
    // Thread t covers 16 B = 2 words: LDS linear [row][word] u64, row = t>>1, wpair = t&1.
    {
        const unsigned long long* MbT = Mbits + (size_t)b * TQv * (TKv / 64)
                                        + (size_t)tile_m * (TKv / 64) + (tile_n >> 6);
        async16((const short*)(MbT + (size_t)(tid >> 1) * (TKv / 64) + (size_t)(tid & 1) * 2),
                (short*)smem + wid * 512);
    }
    __syncthreads();   // drains vmcnt(0)+lgkmcnt(0): slab landed, visible to all

#pragma unroll
    for (int m = 0; m < 8; ++m)
#pragma unroll
        for (int r = 0; r < 4; ++r) {
            int rl = wm * 128 + m * 16 + ((lane >> 4) << 2) + r;   // row - tile_m
            int gm = tile_m + rl;
            unsigned long long bits = *(const unsigned long long*)(smem + rl * 32 + wn * 8);
            float rs = 0.f;
#pragma unroll
            for (int n = 0; n < 4; ++n) {
                // exp2((acc/32 - 4)*log2e) folded: exp2(acc*0.04508422 - 5.77078016)
                float pv = ((bits >> (n * 16 + l15)) & 1ULL)
                               ? exp2f(acc[m][n][r] * 0.04508422f - 5.77078016f) : 0.f;
                rs += pv;
                union { _Float16 h; short sh; } cv;
                cv.h = (_Float16)pv;
                Sb[(size_t)gm * TKv + col0 + n * 16] = cv.sh;
            }
            for (int sh = 1; sh < 16; sh <<= 1) rs += __shfl_xor(rs, sh);
            if (l15 == 0) atomicAdd(&Lb[gm], rs);
        }
}

// ---- pv: O = (P' . Vt^T) / L, fp16 MFMA, fp32 out ----
__global__ __launch_bounds__(512, 2) void pv_kernel(const short* __restrict__ P,
                                                    const short* __restrict__ Vt,
                                                    const float* __restrict__ L,
                                                    float* __restrict__ Out) {
    extern __shared__ char smem[];
    int tid = threadIdx.x;
    int bid = blockIdx.x;
    int b = bid & 7, i = bid >> 3;          // batch -> XCD binding
    int n_t = i & 3, m_t = i >> 2;          // n over HD (4), m over TQv (8)
    int tile_m = m_t * 256, tile_n = n_t * 256;
    const short* Ap = P + (size_t)b * TQv * TKv;
    const short* Bv = Vt + (size_t)b * HD * TKv;
    const float* Lb = L + (size_t)b * TQv;
    f32x4 acc[8][4] = {};
    gemm256_core<true>(Ap + (size_t)tile_m * TKv, Bv + (size_t)tile_n * TKv, TKv, TKv, smem, acc, tid);
    float* Ob = Out + (size_t)b * TQv * HD;
    int wid = tid >> 6, lane = tid & 63;
    int wm = wid >> 2, wn = wid & 3;
    int row0 = tile_m + wm * 128 + ((lane >> 4) << 2);
    int col0 = tile_n + wn * 64 + (lane & 15);

    // ---- R6: stage the 256-row L slab (1 KB) into free LDS via wave 0, replacing
    // 32 serialized dependent global loads per thread with broadcast LDS reads.
    if (tid < 64)
        async16((const short*)(Lb + tile_m + tid * 4), (short*)smem);
    __syncthreads();

#pragma unroll
    for (int m = 0; m < 8; ++m)
#pragma unroll
        for (int r = 0; r < 4; ++r) {
            int rl = wm * 128 + m * 16 + ((lane >> 4) << 2) + r;   // row - tile_m
            int gm = tile_m + rl;
            float l = *(const float*)(smem + rl * 4);
            float inv = (l > 0.f) ? 1.f / l : 0.f;
#pragma unroll
            for (int n = 0; n < 4; ++n)
                Ob[(size_t)gm * HD + col0 + n * 16] = acc[m][n][r] * inv;
        }
}

extern "C" void kernel_launch(void* const* d_in, const int* in_sizes, int n_in,
                              void* d_out, int out_size, void* d_ws, size_t ws_size,
                              hipStream_t stream) {
    const float* query = (const float*)d_in[0];
    const float* enc   = (const float*)d_in[1];
    const int*   mask  = (const int*)d_in[2];
    const float* Wq    = (const float*)d_in[3];
    const float* bq    = (const float*)d_in[4];
    const float* Wk    = (const float*)d_in[5];
    const float* bk    = (const float*)d_in[6];
    const float* Wv    = (const float*)d_in[7];
    const float* bv    = (const float*)d_in[8];
    float* out = (float*)d_out;

    // workspace layout (bytes); total 174,063,616
    //   [0, 6.29MB): Wtq/Wtk/Wtv bf16 (wtrans -> projqk/projv), then reused as
    //     Mbits [0,4MB) + L [4MB,4MB+64KB) once the Wt copies are dead.
    //   S (fp16 P', 67MB) aliases Xq+Xe (dead after projqk/projv).
    char* ws = (char*)d_ws;
    short* Wt  = (short*)(ws);
    unsigned long long* Mbits = (unsigned long long*)(ws);
    float* L   = (float*)(ws + 4194304);
    short* Xq  = (short*)(ws + 6291456);
    short* Xe  = (short*)(ws + 39845888);
    short* S   = (short*)(ws + 6291456);       // aliases Xq,Xe
    short* Qb  = (short*)(ws + 73400320);
    short* Kb  = (short*)(ws + 106954752);
    short* Vt  = (short*)(ws + 140509184);
    (void)in_sizes; (void)n_in; (void)out_size; (void)ws_size;

    // 128 KiB dynamic LDS opt-in (one-time; not a stream op, graph-capture safe)
    static bool inited = false;
    if (!inited) {
        hipFuncSetAttribute((const void*)projqk_kernel, hipFuncAttributeMaxDynamicSharedMemorySize, 131072);
        hipFuncSetAttribute((const void*)projv_kernel,  hipFuncAttributeMaxDynamicSharedMemorySize, 131072);
        hipFuncSetAttribute((const void*)score_kernel,  hipFuncAttributeMaxDynamicSharedMemorySize, 131072);
        hipFuncSetAttribute((const void*)pv_kernel,     hipFuncAttributeMaxDynamicSharedMemorySize, 131072);
        inited = true;
    }

    convert_kernel<<<dim3(8192, 2), 256, 0, stream>>>(query, enc, Xq, Xe);
    wtrans_kernel<<<dim3(32, 32, 3), dim3(32, 8), 0, stream>>>(Wq, Wk, Wv, Wt);
    projqk_kernel<<<dim3(256, 1, 2), 512, 131072, stream>>>(Xq, Xe, Wt, bq, bk, Qb, Kb);
    projv_kernel<<<dim3(256), 512, 131072, stream>>>(Xe, Wt + (size_t)2 * HD * FD, bv, Vt);
    maskbits_kernel<<<dim3(2048), 256, 0, stream>>>(mask, Mbits, L);
    score_kernel<<<dim3(512), 512, 131072, stream>>>(Qb, Kb, Mbits, S, L);
    pv_kernel<<<dim3(256), 512, 131072, stream>>>(S, Vt, L, out);
}

// Round 7
// 562.386 us; speedup vs baseline: 1.4139x; 1.0286x over previous
//
#include <hip/hip_runtime.h>

#define NB 8
#define TQv 2048
#define TKv 2048
#define FD 1024
#define HD 1024

typedef __attribute__((ext_vector_type(8))) short short8;
typedef __attribute__((ext_vector_type(8))) _Float16 half8;
typedef __attribute__((ext_vector_type(4))) float f32x4;

// round-to-nearest-even fp32 -> bf16 (finite inputs only)
__device__ __forceinline__ short f2bf(float f) {
    union { float f; unsigned u; } v; v.f = f;
    unsigned r = v.u + 0x7FFFu + ((v.u >> 16) & 1u);
    return (short)(r >> 16);
}

__device__ __forceinline__ half8 as_h8(short8 v) {
    union { short8 s; half8 h; } u; u.s = v; return u.h;
}

// async 16B global -> LDS (global_load_lds_dwordx4); LDS dest = wave-uniform base + lane*16
__device__ __forceinline__ void async16(const short* g, short* l) {
    __builtin_amdgcn_global_load_lds(
        (const __attribute__((address_space(1))) unsigned int*)g,
        (__attribute__((address_space(3))) unsigned int*)l, 16, 0, 0);
}

// 32-bit LDS byte offset of a generic pointer into __shared__
__device__ __forceinline__ unsigned lds_off(void* p) {
    return (unsigned)(unsigned long long)(__attribute__((address_space(3))) char*)p;
}

#define BAR  __builtin_amdgcn_s_barrier()
#define SP1  __builtin_amdgcn_s_setprio(1)
#define SP0  __builtin_amdgcn_s_setprio(0)
#define SCB  __builtin_amdgcn_sched_barrier(0)
#define VMCNT(N) asm volatile("s_waitcnt vmcnt(" #N ")" ::: "memory")
#define LGKC(N)  asm volatile("s_waitcnt lgkmcnt(" #N ")" ::: "memory")

// ds_read_b128 as INLINE ASM: opaque to the memory legalizer, so hipcc cannot insert
// conservative s_waitcnt vmcnt(0) before LDS reads that might alias in-flight
// global_load_lds writes. Completion enforced manually: counted LGKC + sched_barrier(0).
#define DSR(dst, addr, OFS) \
    asm volatile("ds_read_b128 %0, %1 offset:" OFS : "=v"(dst) : "v"(addr))

// ============ 256x256 6-phase GEMM core (T2+T3+T4+T5, asm-ds_read) ============
// NT: C[m][n] = sum_k A[m][k]*B[n][k]. 512 thr = 8 waves (2M x 4N); wave C = 128x64
// = acc[8][4] f32x4; 16x16x32 MFMA; BK=64; K-tiles double-buffered in 128 KiB LDS:
// buf{0,1} x [ A 256x64 (2 halves of 128 rows) | B 256x64 ] bf16, XOR swizzle
// (verified: SQ_LDS_BANK_CONFLICT == 0):
//   element (r,k) of a half -> 16B block L = 8r + ((k>>3)^(r&7)), byte (k&7)*2;
//   stage call = 8KB = 64 rows, lane covers row lr=l>>3, src chunk kc=(l&7)^lr.
// ROUND-7 PHASE-MERGE: former P4/P8 (no ds_reads) folded into P3/P7 -> 6 phases,
// 12 barriers/iter (was 16), 32-MFMA clusters at P3'/P7'.
// Stage ledger (tiles a=2i->buf0, b=a+1->buf1):
//   P1: b.B0   P2: b.B1   P3': a2.A0+a2.A1 + VMCNT(4)
//   P5: a2.B0  P6: a2.B1  P7': b2.A0+b2.A1 + VMCNT(4)
// WAR: A-lo last read P1 (drained pre-P1-close), A-hi last read P2 (drained
// pre-P2-close) -> both stages at P3' (after P2-close) safe; B halves last read
// P1/P3' (buf0) or P5/P7' (buf1), restaged >=2 closing barriers later. Mirror for P7'.
// RAW: VMCNT(4) before P3'/P7' closing barrier leaves exactly the 4 newest (A-stage)
// loads outstanding => prior A + B0 + B1 of the next-computed tile all landed, then
// the barrier publishes cross-wave. Last iter: VMCNT(0)@P3' (8 outstanding, no stages).
#define RD_ALO(BF) { DSR(aQ0[0][0], adA0[BF], "0");    DSR(aQ0[0][1], adA1[BF], "0"); \
                     DSR(aQ0[1][0], adA0[BF], "2048"); DSR(aQ0[1][1], adA1[BF], "2048"); \
                     DSR(aQ0[2][0], adA0[BF], "4096"); DSR(aQ0[2][1], adA1[BF], "4096"); \
                     DSR(aQ0[3][0], adA0[BF], "6144"); DSR(aQ0[3][1], adA1[BF], "6144"); }
#define RD_AHI(BF) { DSR(aQ1[0][0], adA0[BF], "8192");  DSR(aQ1[0][1], adA1[BF], "8192"); \
                     DSR(aQ1[1][0], adA0[BF], "10240"); DSR(aQ1[1][1], adA1[BF], "10240"); \
                     DSR(aQ1[2][0], adA0[BF], "12288"); DSR(aQ1[2][1], adA1[BF], "12288"); \
                     DSR(aQ1[3][0], adA0[BF], "14336"); DSR(aQ1[3][1], adA1[BF], "14336"); }
#define RD_BLO(BF) { DSR(bQ0[0][0], adB0[BF], "0");    DSR(bQ0[0][1], adB1[BF], "0"); \
                     DSR(bQ0[1][0], adB0[BF], "2048"); DSR(bQ0[1][1], adB1[BF], "2048"); }
#define RD_BHI(BF) { DSR(bQ1[0][0], adB0[BF], "4096"); DSR(bQ1[0][1], adB1[BF], "4096"); \
                     DSR(bQ1[1][0], adB0[BF], "6144"); DSR(bQ1[1][1], adB1[BF], "6144"); }

#define QMFMA(AQ, BQ, MO, NO) { \
    _Pragma("unroll") for (int ks = 0; ks < 2; ++ks) \
    _Pragma("unroll") for (int f = 0; f < 4; ++f) \
    _Pragma("unroll") for (int n = 0; n < 2; ++n) { \
        if constexpr (F16) \
            acc[(MO)+f][(NO)+n] = __builtin_amdgcn_mfma_f32_16x16x32_f16( \
                as_h8(AQ[f][ks]), as_h8(BQ[n][ks]), acc[(MO)+f][(NO)+n], 0, 0, 0); \
        else \
            acc[(MO)+f][(NO)+n] = __builtin_amdgcn_mfma_f32_16x16x32_bf16( \
                AQ[f][ks], BQ[n][ks], acc[(MO)+f][(NO)+n], 0, 0, 0); } }

// stage one half-tile (2 x async16); REL/tofs in shorts (k-units)
#define STG_A(BF, H, REL) { \
    async16(gaBase + sH[2*(H)+0] + tofs + (REL), lbase + (BF)*32768 + (H)*8192); \
    async16(gaBase + sH[2*(H)+1] + tofs + (REL), lbase + (BF)*32768 + (H)*8192 + 4096); }
#define STG_B(BF, H, REL) { \
    async16(gbBase + sH[2*(H)+0] + tofs + (REL), lbase + (BF)*32768 + 16384 + (H)*8192); \
    async16(gbBase + sH[2*(H)+1] + tofs + (REL), lbase + (BF)*32768 + 16384 + (H)*8192 + 4096); }

template <bool F16>
__device__ __forceinline__ void gemm256_core(const short* __restrict__ A,
                                             const short* __restrict__ B,
                                             int ld, int K, char* smem,
                                             f32x4 acc[8][4], int tid) {
    const int wid = tid >> 6, lane = tid & 63;
    const int wm = wid >> 2, wn = wid & 3;
    const int l15 = lane & 15;

    // staging: per-thread global base + SGPR row-window offsets
    const int kc8 = ((lane & 7) ^ (lane >> 3)) * 8;
    const short* gaBase = A + (size_t)(wid * 8 + (lane >> 3)) * ld + kc8;
    const short* gbBase = B + (size_t)(wid * 8 + (lane >> 3)) * ld + kc8;
    size_t sH[4];
#pragma unroll
    for (int k = 0; k < 4; ++k) sH[k] = (size_t)k * 64 * ld;
    short* lbase = (short*)smem + wid * 512;

    // loop-invariant 32-bit LDS read addresses (ks0/ks1 swizzled chunk, per buf)
    const int o0 = (((lane >> 4)    ) ^ (lane & 7)) * 16;
    const int o1 = (((lane >> 4) + 4) ^ (lane & 7)) * 16;
    unsigned aB_ = lds_off(smem) + wm * 16384 + l15 * 128;
    unsigned bB_ = lds_off(smem) + 32768 + (wn >> 1) * 16384 + (wn & 1) * 8192 + l15 * 128;
    unsigned adA0[2] = { aB_ + o0, aB_ + o0 + 65536u };
    unsigned adA1[2] = { aB_ + o1, aB_ + o1 + 65536u };
    unsigned adB0[2] = { bB_ + o0, bB_ + o0 + 65536u };
    unsigned adB1[2] = { bB_ + o1, bB_ + o1 + 65536u };

    int tofs = 0;
    // prologue: tile0 full -> buf0, tile1 A halves -> buf1
    STG_A(0, 0, 0); STG_A(0, 1, 0); STG_B(0, 0, 0); STG_B(0, 1, 0);
    STG_A(1, 0, 64); STG_A(1, 1, 64);
    SCB; VMCNT(4); BAR; SCB;

    short8 aQ0[4][2], aQ1[4][2], bQ0[2][2], bQ1[2][2];
    const int niter = K >> 7;
    for (int it = 0; it < niter; ++it) {
        const bool nl = (it != niter - 1);
        // P1
        RD_ALO(0); RD_BLO(0);
        STG_B(1, 0, 64);
        SCB; LGKC(8); BAR; LGKC(0); SCB;
        SP1; QMFMA(aQ0, bQ0, 0, 0); SP0; SCB; BAR; SCB;
        // P2
        RD_AHI(0);
        STG_B(1, 1, 64);
        SCB; BAR; LGKC(0); SCB;
        SP1; QMFMA(aQ1, bQ0, 4, 0); SP0; SCB; BAR; SCB;
        // P3' (merged P3+P4): 32-MFMA cluster
        RD_BHI(0);
        if (nl) { STG_A(0, 0, 128); STG_A(0, 1, 128); }
        SCB; BAR; LGKC(0); SCB;
        SP1; QMFMA(aQ0, bQ1, 0, 2); QMFMA(aQ1, bQ1, 4, 2); SP0; SCB;
        if (nl) { VMCNT(4); } else { VMCNT(0); }
        BAR; SCB;
        // P5
        RD_ALO(1); RD_BLO(1);
        if (nl) STG_B(0, 0, 128);
        SCB; LGKC(8); BAR; LGKC(0); SCB;
        SP1; QMFMA(aQ0, bQ0, 0, 0); SP0; SCB; BAR; SCB;
        // P6
        RD_AHI(1);
        if (nl) STG_B(0, 1, 128);
        SCB; BAR; LGKC(0); SCB;
        SP1; QMFMA(aQ1, bQ0, 4, 0); SP0; SCB; BAR; SCB;
        // P7' (merged P7+P8): 32-MFMA cluster
        RD_BHI(1);
        if (nl) { STG_A(1, 0, 192); STG_A(1, 1, 192); }
        SCB; BAR; LGKC(0); SCB;
        SP1; QMFMA(aQ0, bQ1, 0, 2); QMFMA(aQ1, bQ1, 4, 2); SP0; SCB;
        if (nl) VMCNT(4);
        BAR; SCB;
        tofs += 128;
    }
}

// C/D layout per 16x16x32 frag (m89/m91): col = lane&15, row = 4*(lane>>4) + r
// global: row = tile_m + wm*128 + m*16 + 4*(lane>>4) + r ; col = tile_n + wn*64 + n*16 + (lane&15)

// ---- R7 merged prep kernel: convert (fp32->bf16) + wtrans (W^T bf16) + maskbits ----
// Roles by blockIdx.x range; the three are independent and all memory-bound, so one
// launch lets them share HBM BW instead of serializing (~60us -> ~40us).
#define CONV_BLKS 16384
#define WT_BLKS   3072
#define MB_START  (CONV_BLKS + WT_BLKS)
__global__ __launch_bounds__(256) void prep_kernel(const float* __restrict__ q,
                                                   const float* __restrict__ e,
                                                   const float* __restrict__ Wq,
                                                   const float* __restrict__ Wk,
                                                   const float* __restrict__ Wv,
                                                   const int* __restrict__ mask,
                                                   short* __restrict__ xq,
                                                   short* __restrict__ xe,
                                                   short* __restrict__ Wt,
                                                   unsigned long long* __restrict__ Mbits,
                                                   float* __restrict__ L) {
    __shared__ float tile[32][33];
    int bid = blockIdx.x, tid = threadIdx.x;
    if (bid < CONV_BLKS) {
        // convert: 8 floats/thread
        size_t i = (size_t)(bid & 8191) * 256 + tid;
        const float* src = (bid >> 13) ? e : q;
        short* dst = (bid >> 13) ? xe : xq;
        float4 a = ((const float4*)src)[2 * i];
        float4 b = ((const float4*)src)[2 * i + 1];
        short8 v;
        v[0] = f2bf(a.x); v[1] = f2bf(a.y); v[2] = f2bf(a.z); v[3] = f2bf(a.w);
        v[4] = f2bf(b.x); v[5] = f2bf(b.y); v[6] = f2bf(b.z); v[7] = f2bf(b.w);
        ((short8*)dst)[i] = v;
    } else if (bid < MB_START) {
        // wtrans: 32x32 tile transpose, z picks Wq/Wk/Wv
        int t = bid - CONV_BLKS;
        int z = t >> 10, r2 = t & 1023;
        const float* W = (z == 0) ? Wq : (z == 1) ? Wk : Wv;
        short* dst = Wt + (size_t)z * HD * FD;
        int h0 = (r2 & 31) * 32, f0 = (r2 >> 5) * 32;
        int tx = tid & 31, ty = tid >> 5;
        for (int j = ty; j < 32; j += 8)
            tile[j][tx] = W[(size_t)(f0 + j) * HD + h0 + tx];
        __syncthreads();
        for (int j = ty; j < 32; j += 8)
            dst[(size_t)(h0 + j) * FD + f0 + tx] = f2bf(tile[tx][j]);
    } else {
        // maskbits: int32 -> u64 ballot bitmask, + zero L
        int mb = bid - MB_START;
        int lane = tid & 63;
        if (mb < 64) L[mb * 256 + tid] = 0.f;
        const int NW = NB * TQv * (TKv / 64);
        int stride = 2048 * 4;
        for (int w = mb * 4 + (tid >> 6); w < NW; w += stride) {
            int v = mask[(size_t)w * 64 + lane];
            unsigned long long bal = __ballot(v != 0);
            if (lane == 0) Mbits[w] = bal;
        }
    }
}

// ---- Q/K projections: 256x256 tiles over [16384 x 1024] ----
__global__ __launch_bounds__(512, 2) void projqk_kernel(const short* __restrict__ Xq,
                                                        const short* __restrict__ Xe,
                                                        const short* __restrict__ Wt3,
                                                        const float* __restrict__ bq,
                                                        const float* __restrict__ bk,
                                                        short* __restrict__ Q,
                                                        short* __restrict__ K) {
    extern __shared__ char smem[];
    int tid = threadIdx.x;
    int p = blockIdx.z;
    const short* X = p ? Xe : Xq;
    const short* Wt = Wt3 + (size_t)p * HD * FD;
    const float* bias = p ? bk : bq;
    short* O = p ? K : Q;
    int bid = blockIdx.x;                   // XCD swizzle: m-groups bound to XCDs
    int xcd = bid & 7, idx = bid >> 3;
    int n_t = idx & 3, m_t = (idx >> 2) * 8 + xcd;
    int tile_m = m_t * 256, tile_n = n_t * 256;
    f32x4 acc[8][4] = {};
    gemm256_core<false>(X + (size_t)tile_m * FD, Wt + (size_t)tile_n * FD, FD, FD, smem, acc, tid);
    int wid = tid >> 6, lane = tid & 63;
    int wm = wid >> 2, wn = wid & 3;
    int row0 = tile_m + wm * 128 + ((lane >> 4) << 2);
    int col0 = tile_n + wn * 64 + (lane & 15);
    // R7: n-INNER store order (4 consecutive 32B chunks per row -> write-combine,
    // kills the 2x WRITE_SIZE amplification seen in r6: 130MB vs 67MB ideal)
    float bv4[4];
#pragma unroll
    for (int n = 0; n < 4; ++n) bv4[n] = bias[col0 + n * 16];
#pragma unroll
    for (int m = 0; m < 8; ++m)
#pragma unroll
        for (int r = 0; r < 4; ++r) {
            size_t rowb = (size_t)(row0 + m * 16 + r) * HD;
#pragma unroll
            for (int n = 0; n < 4; ++n)
                O[rowb + col0 + n * 16] = f2bf(acc[m][n][r] + bv4[n]);
        }
}

// ---- V projection, transposed natively: Vt[b][h][t] = Wtv[h,:].Xe[b,t,:] + bv[h], fp16 out ----
__global__ __launch_bounds__(512, 2) void projv_kernel(const short* __restrict__ Xe,
                                                       const short* __restrict__ Wtv,
                                                       const float* __restrict__ bv,
                                                       short* __restrict__ Vt) {
    extern __shared__ char smem[];
    int tid = threadIdx.x;
    int bid = blockIdx.x;
    int b = bid & 7, i = bid >> 3;          // batch -> XCD binding
    int m_t = i & 3, n_t = i >> 2;          // m over HD (4), n over TKv (8)
    int tile_m = m_t * 256, tile_n = n_t * 256;
    const short* Xb = Xe + (size_t)b * TKv * FD;
    f32x4 acc[8][4] = {};
    gemm256_core<false>(Wtv + (size_t)tile_m * FD, Xb + (size_t)tile_n * FD, FD, FD, smem, acc, tid);
    short* Ob = Vt + (size_t)b * HD * TKv;
    int wid = tid >> 6, lane = tid & 63;
    int wm = wid >> 2, wn = wid & 3;
    int row0 = tile_m + wm * 128 + ((lane >> 4) << 2);
    int col0 = tile_n + wn * 64 + (lane & 15);
#pragma unroll
    for (int m = 0; m < 8; ++m)
#pragma unroll
        for (int r = 0; r < 4; ++r) {
            int gm = row0 + m * 16 + r;     // h
            float bv_ = bv[gm];
#pragma unroll
            for (int n = 0; n < 4; ++n) {
                union { _Float16 h; short s; } cv;
                cv.h = (_Float16)(acc[m][n][r] + bv_);
                Ob[(size_t)gm * TKv + col0 + n * 16] = cv.s;
            }
        }
}

// ---- score: P' = mask ? exp(QK/32 - 4) : 0 (fp16), row partials -> atomicAdd L ----
__global__ __launch_bounds__(512, 2) void score_kernel(const short* __restrict__ Q,
                                                       const short* __restrict__ K,
                                                       const unsigned long long* __restrict__ Mbits,
                                                       short* __restrict__ S,
                                                       float* __restrict__ L) {
    extern __shared__ char smem[];
    int tid = threadIdx.x;
    int bid = blockIdx.x;
    int b = bid & 7, i = bid >> 3;          // batch -> XCD binding
    int n_t = i & 7, m_t = i >> 3;
    int tile_m = m_t * 256, tile_n = n_t * 256;
    const short* Aq = Q + (size_t)b * TQv * HD;
    const short* Bk = K + (size_t)b * TKv * HD;
    f32x4 acc[8][4] = {};
    gemm256_core<false>(Aq + (size_t)tile_m * HD, Bk + (size_t)tile_n * HD, HD, HD, smem, acc, tid);
    short* Sb = S + (size_t)b * TQv * TKv;
    float* Lb = L + (size_t)b * TQv;
    int wid = tid >> 6, lane = tid & 63;
    int wm = wid >> 2, wn = wid & 3;
    int l15 = lane & 15;
    int row0 = tile_m + wm * 128 + ((lane >> 4) << 2);
    int col0 = tile_n + wn * 64 + l15;

    // stage this block's Mbits slab (256 rows x 4 words = 8 KB) into now-free LDS
    // with one coalesced global_load_lds burst (kills the serialized load chain).
    {
        const unsigned long long* MbT = Mbits + (size_t)b * TQv * (TKv / 64)
                                        + (size_t)tile_m * (TKv / 64) + (tile_n >> 6);
        async16((const short*)(MbT + (size_t)(tid >> 1) * (TKv / 64) + (size_t)(tid & 1) * 2),
                (short*)smem + wid * 512);
    }
    __syncthreads();   // drains vmcnt(0)+lgkmcnt(0): slab landed, visible to all

#pragma unroll
    for (int m = 0; m < 8; ++m)
#pragma unroll
        for (int r = 0; r < 4; ++r) {
            int rl = wm * 128 + m * 16 + ((lane >> 4) << 2) + r;   // row - tile_m
            int gm = tile_m + rl;
            unsigned long long bits = *(const unsigned long long*)(smem + rl * 32 + wn * 8);
            float rs = 0.f;
#pragma unroll
            for (int n = 0; n < 4; ++n) {
                // exp2((acc/32 - 4)*log2e) folded: exp2(acc*0.04508422 - 5.77078016)
                float pv = ((bits >> (n * 16 + l15)) & 1ULL)
                               ? exp2f(acc[m][n][r] * 0.04508422f - 5.77078016f) : 0.f;
                rs += pv;
                union { _Float16 h; short sh; } cv;
                cv.h = (_Float16)pv;
                Sb[(size_t)gm * TKv + col0 + n * 16] = cv.sh;
            }
            for (int sh = 1; sh < 16; sh <<= 1) rs += __shfl_xor(rs, sh);
            if (l15 == 0) atomicAdd(&Lb[gm], rs);
        }
}

// ---- pv: O = (P' . Vt^T) / L, fp16 MFMA, fp32 out ----
__global__ __launch_bounds__(512, 2) void pv_kernel(const short* __restrict__ P,
                                                    const short* __restrict__ Vt,
                                                    const float* __restrict__ L,
                                                    float* __restrict__ Out) {
    extern __shared__ char smem[];
    int tid = threadIdx.x;
    int bid = blockIdx.x;
    int b = bid & 7, i = bid >> 3;          // batch -> XCD binding
    int n_t = i & 3, m_t = i >> 2;          // n over HD (4), m over TQv (8)
    int tile_m = m_t * 256, tile_n = n_t * 256;
    const short* Ap = P + (size_t)b * TQv * TKv;
    const short* Bv = Vt + (size_t)b * HD * TKv;
    const float* Lb = L + (size_t)b * TQv;
    f32x4 acc[8][4] = {};
    gemm256_core<true>(Ap + (size_t)tile_m * TKv, Bv + (size_t)tile_n * TKv, TKv, TKv, smem, acc, tid);
    float* Ob = Out + (size_t)b * TQv * HD;
    int wid = tid >> 6, lane = tid & 63;
    int wm = wid >> 2, wn = wid & 3;
    int row0 = tile_m + wm * 128 + ((lane >> 4) << 2);
    int col0 = tile_n + wn * 64 + (lane & 15);

    // stage the 256-row L slab (1 KB) into free LDS via wave 0 (broadcast reads after)
    if (tid < 64)
        async16((const short*)(Lb + tile_m + tid * 4), (short*)smem);
    __syncthreads();

#pragma unroll
    for (int m = 0; m < 8; ++m)
#pragma unroll
        for (int r = 0; r < 4; ++r) {
            int rl = wm * 128 + m * 16 + ((lane >> 4) << 2) + r;   // row - tile_m
            int gm = tile_m + rl;
            float l = *(const float*)(smem + rl * 4);
            float inv = (l > 0.f) ? 1.f / l : 0.f;
#pragma unroll
            for (int n = 0; n < 4; ++n)
                Ob[(size_t)gm * HD + col0 + n * 16] = acc[m][n][r] * inv;
        }
}

extern "C" void kernel_launch(void* const* d_in, const int* in_sizes, int n_in,
                              void* d_out, int out_size, void* d_ws, size_t ws_size,
                              hipStream_t stream) {
    const float* query = (const float*)d_in[0];
    const float* enc   = (const float*)d_in[1];
    const int*   mask  = (const int*)d_in[2];
    const float* Wq    = (const float*)d_in[3];
    const float* bq    = (const float*)d_in[4];
    const float* Wk    = (const float*)d_in[5];
    const float* bk    = (const float*)d_in[6];
    const float* Wv    = (const float*)d_in[7];
    const float* bv    = (const float*)d_in[8];
    float* out = (float*)d_out;

    // workspace layout (bytes); total 174,063,616
    //   [0, 6.29MB): Wtq/Wtk/Wtv bf16.  Mbits lives at [4.25MB..) region? NO —
    //   NOTE (R7): prep computes Wt AND Mbits in one launch, so they must not alias.
    //   New layout: Mbits [0,2MB) ... actually Mbits = 8*2048*32*8B = 4MB.
    //   Keep: Mbits [0,4MB), L [4MB,4.0625MB), Wt [4.0625MB, 10.35MB), rest shifted.
    char* ws = (char*)d_ws;
    unsigned long long* Mbits = (unsigned long long*)(ws);
    float* L   = (float*)(ws + 4194304);
    short* Wt  = (short*)(ws + 4259840);
    short* Xq  = (short*)(ws + 10551296);
    short* Xe  = (short*)(ws + 44105728);
    short* S   = (short*)(ws + 10551296);      // aliases Xq,Xe (dead after projqk/projv)
    short* Qb  = (short*)(ws + 77660160);
    short* Kb  = (short*)(ws + 111214592);
    short* Vt  = (short*)(ws + 144769024);
    (void)in_sizes; (void)n_in; (void)out_size; (void)ws_size;

    // 128 KiB dynamic LDS opt-in (one-time; not a stream op, graph-capture safe)
    static bool inited = false;
    if (!inited) {
        hipFuncSetAttribute((const void*)projqk_kernel, hipFuncAttributeMaxDynamicSharedMemorySize, 131072);
        hipFuncSetAttribute((const void*)projv_kernel,  hipFuncAttributeMaxDynamicSharedMemorySize, 131072);
        hipFuncSetAttribute((const void*)score_kernel,  hipFuncAttributeMaxDynamicSharedMemorySize, 131072);
        hipFuncSetAttribute((const void*)pv_kernel,     hipFuncAttributeMaxDynamicSharedMemorySize, 131072);
        inited = true;
    }

    prep_kernel<<<dim3(CONV_BLKS + WT_BLKS + 2048), 256, 0, stream>>>(
        query, enc, Wq, Wk, Wv, mask, Xq, Xe, Wt, Mbits, L);
    projqk_kernel<<<dim3(256, 1, 2), 512, 131072, stream>>>(Xq, Xe, Wt, bq, bk, Qb, Kb);
    projv_kernel<<<dim3(256), 512, 131072, stream>>>(Xe, Wt + (size_t)2 * HD * FD, bv, Vt);
    score_kernel<<<dim3(512), 512, 131072, stream>>>(Qb, Kb, Mbits, S, L);
    pv_kernel<<<dim3(256), 512, 131072, stream>>>(S, Vt, L, out);
}

// Round 8
// 541.412 us; speedup vs baseline: 1.4686x; 1.0387x over previous
//
#include <hip/hip_runtime.h>

#define NB 8
#define TQv 2048
#define TKv 2048
#define FD 1024
#define HD 1024

typedef __attribute__((ext_vector_type(8))) short short8;
typedef __attribute__((ext_vector_type(8))) _Float16 half8;
typedef __attribute__((ext_vector_type(4))) float f32x4;

// round-to-nearest-even fp32 -> bf16 (finite inputs only)
__device__ __forceinline__ short f2bf(float f) {
    union { float f; unsigned u; } v; v.f = f;
    unsigned r = v.u + 0x7FFFu + ((v.u >> 16) & 1u);
    return (short)(r >> 16);
}

__device__ __forceinline__ half8 as_h8(short8 v) {
    union { short8 s; half8 h; } u; u.s = v; return u.h;
}

// async 16B global -> LDS (global_load_lds_dwordx4); LDS dest = wave-uniform base + lane*16
__device__ __forceinline__ void async16(const short* g, short* l) {
    __builtin_amdgcn_global_load_lds(
        (const __attribute__((address_space(1))) unsigned int*)g,
        (__attribute__((address_space(3))) unsigned int*)l, 16, 0, 0);
}

// 32-bit LDS byte offset of a generic pointer into __shared__
__device__ __forceinline__ unsigned lds_off(void* p) {
    return (unsigned)(unsigned long long)(__attribute__((address_space(3))) char*)p;
}

#define BAR  __builtin_amdgcn_s_barrier()
#define SP1  __builtin_amdgcn_s_setprio(1)
#define SP0  __builtin_amdgcn_s_setprio(0)
#define SCB  __builtin_amdgcn_sched_barrier(0)
#define VMCNT(N) asm volatile("s_waitcnt vmcnt(" #N ")" ::: "memory")
#define LGKC(N)  asm volatile("s_waitcnt lgkmcnt(" #N ")" ::: "memory")

// ds_read_b128 as INLINE ASM: opaque to the memory legalizer, so hipcc cannot insert
// conservative s_waitcnt vmcnt(0) before LDS reads that might alias in-flight
// global_load_lds writes. Completion enforced manually: counted LGKC + sched_barrier(0).
#define DSR(dst, addr, OFS) \
    asm volatile("ds_read_b128 %0, %1 offset:" OFS : "=v"(dst) : "v"(addr))

// ============ 256x256 6-phase GEMM core (T2+T3+T4+T5, asm-ds_read) ============
// NT: C[m][n] = sum_k A[m][k]*B[n][k]. 512 thr = 8 waves (2M x 4N); wave C = 128x64
// = acc[8][4] f32x4; 16x16x32 MFMA; BK=64; K-tiles double-buffered in 128 KiB LDS:
// buf{0,1} x [ A 256x64 (2 halves of 128 rows) | B 256x64 ] bf16, XOR swizzle
// (verified: SQ_LDS_BANK_CONFLICT == 0):
//   element (r,k) of a half -> 16B block L = 8r + ((k>>3)^(r&7)), byte (k&7)*2;
//   stage call = 8KB = 64 rows, lane covers row lr=l>>3, src chunk kc=(l&7)^lr.
// 6 phases, 12 barriers/iter, 32-MFMA clusters at P3'/P7'.
// Stage ledger (tiles a=2i->buf0, b=a+1->buf1):
//   P1: b.B0   P2: b.B1   P3': a2.A0+a2.A1 + VMCNT(4)
//   P5: a2.B0  P6: a2.B1  P7': b2.A0+b2.A1 + VMCNT(4)
// WAR: A-lo last read P1, A-hi last read P2 -> stages at P3' (after P2-close) safe;
// B halves restaged >=2 closing barriers after last read. Mirror for P7'.
// RAW: VMCNT(4) before P3'/P7' closing barrier leaves exactly the 4 newest (A-stage)
// loads outstanding => the next-computed tile is fully landed; barrier publishes.
// Last iter: VMCNT(0)@P3'.
#define RD_ALO(BF) { DSR(aQ0[0][0], adA0[BF], "0");    DSR(aQ0[0][1], adA1[BF], "0"); \
                     DSR(aQ0[1][0], adA0[BF], "2048"); DSR(aQ0[1][1], adA1[BF], "2048"); \
                     DSR(aQ0[2][0], adA0[BF], "4096"); DSR(aQ0[2][1], adA1[BF], "4096"); \
                     DSR(aQ0[3][0], adA0[BF], "6144"); DSR(aQ0[3][1], adA1[BF], "6144"); }
#define RD_AHI(BF) { DSR(aQ1[0][0], adA0[BF], "8192");  DSR(aQ1[0][1], adA1[BF], "8192"); \
                     DSR(aQ1[1][0], adA0[BF], "10240"); DSR(aQ1[1][1], adA1[BF], "10240"); \
                     DSR(aQ1[2][0], adA0[BF], "12288"); DSR(aQ1[2][1], adA1[BF], "12288"); \
                     DSR(aQ1[3][0], adA0[BF], "14336"); DSR(aQ1[3][1], adA1[BF], "14336"); }
#define RD_BLO(BF) { DSR(bQ0[0][0], adB0[BF], "0");    DSR(bQ0[0][1], adB1[BF], "0"); \
                     DSR(bQ0[1][0], adB0[BF], "2048"); DSR(bQ0[1][1], adB1[BF], "2048"); }
#define RD_BHI(BF) { DSR(bQ1[0][0], adB0[BF], "4096"); DSR(bQ1[0][1], adB1[BF], "4096"); \
                     DSR(bQ1[1][0], adB0[BF], "6144"); DSR(bQ1[1][1], adB1[BF], "6144"); }

#define QMFMA(AQ, BQ, MO, NO) { \
    _Pragma("unroll") for (int ks = 0; ks < 2; ++ks) \
    _Pragma("unroll") for (int f = 0; f < 4; ++f) \
    _Pragma("unroll") for (int n = 0; n < 2; ++n) { \
        if constexpr (F16) \
            acc[(MO)+f][(NO)+n] = __builtin_amdgcn_mfma_f32_16x16x32_f16( \
                as_h8(AQ[f][ks]), as_h8(BQ[n][ks]), acc[(MO)+f][(NO)+n], 0, 0, 0); \
        else \
            acc[(MO)+f][(NO)+n] = __builtin_amdgcn_mfma_f32_16x16x32_bf16( \
                AQ[f][ks], BQ[n][ks], acc[(MO)+f][(NO)+n], 0, 0, 0); } }

// stage one half-tile (2 x async16); REL/tofs in shorts (k-units)
#define STG_A(BF, H, REL) { \
    async16(gaBase + sH[2*(H)+0] + tofs + (REL), lbase + (BF)*32768 + (H)*8192); \
    async16(gaBase + sH[2*(H)+1] + tofs + (REL), lbase + (BF)*32768 + (H)*8192 + 4096); }
#define STG_B(BF, H, REL) { \
    async16(gbBase + sH[2*(H)+0] + tofs + (REL), lbase + (BF)*32768 + 16384 + (H)*8192); \
    async16(gbBase + sH[2*(H)+1] + tofs + (REL), lbase + (BF)*32768 + 16384 + (H)*8192 + 4096); }

template <bool F16>
__device__ __forceinline__ void gemm256_core(const short* __restrict__ A,
                                             const short* __restrict__ B,
                                             int ld, int K, char* smem,
                                             f32x4 acc[8][4], int tid) {
    const int wid = tid >> 6, lane = tid & 63;
    const int wm = wid >> 2, wn = wid & 3;
    const int l15 = lane & 15;

    // staging: per-thread global base + SGPR row-window offsets
    const int kc8 = ((lane & 7) ^ (lane >> 3)) * 8;
    const short* gaBase = A + (size_t)(wid * 8 + (lane >> 3)) * ld + kc8;
    const short* gbBase = B + (size_t)(wid * 8 + (lane >> 3)) * ld + kc8;
    size_t sH[4];
#pragma unroll
    for (int k = 0; k < 4; ++k) sH[k] = (size_t)k * 64 * ld;
    short* lbase = (short*)smem + wid * 512;

    // loop-invariant 32-bit LDS read addresses (ks0/ks1 swizzled chunk, per buf)
    const int o0 = (((lane >> 4)    ) ^ (lane & 7)) * 16;
    const int o1 = (((lane >> 4) + 4) ^ (lane & 7)) * 16;
    unsigned aB_ = lds_off(smem) + wm * 16384 + l15 * 128;
    unsigned bB_ = lds_off(smem) + 32768 + (wn >> 1) * 16384 + (wn & 1) * 8192 + l15 * 128;
    unsigned adA0[2] = { aB_ + o0, aB_ + o0 + 65536u };
    unsigned adA1[2] = { aB_ + o1, aB_ + o1 + 65536u };
    unsigned adB0[2] = { bB_ + o0, bB_ + o0 + 65536u };
    unsigned adB1[2] = { bB_ + o1, bB_ + o1 + 65536u };

    int tofs = 0;
    // prologue: tile0 full -> buf0, tile1 A halves -> buf1
    STG_A(0, 0, 0); STG_A(0, 1, 0); STG_B(0, 0, 0); STG_B(0, 1, 0);
    STG_A(1, 0, 64); STG_A(1, 1, 64);
    SCB; VMCNT(4); BAR; SCB;

    short8 aQ0[4][2], aQ1[4][2], bQ0[2][2], bQ1[2][2];
    const int niter = K >> 7;
    for (int it = 0; it < niter; ++it) {
        const bool nl = (it != niter - 1);
        // P1
        RD_ALO(0); RD_BLO(0);
        STG_B(1, 0, 64);
        SCB; LGKC(8); BAR; LGKC(0); SCB;
        SP1; QMFMA(aQ0, bQ0, 0, 0); SP0; SCB; BAR; SCB;
        // P2
        RD_AHI(0);
        STG_B(1, 1, 64);
        SCB; BAR; LGKC(0); SCB;
        SP1; QMFMA(aQ1, bQ0, 4, 0); SP0; SCB; BAR; SCB;
        // P3' (merged): 32-MFMA cluster
        RD_BHI(0);
        if (nl) { STG_A(0, 0, 128); STG_A(0, 1, 128); }
        SCB; BAR; LGKC(0); SCB;
        SP1; QMFMA(aQ0, bQ1, 0, 2); QMFMA(aQ1, bQ1, 4, 2); SP0; SCB;
        if (nl) { VMCNT(4); } else { VMCNT(0); }
        BAR; SCB;
        // P5
        RD_ALO(1); RD_BLO(1);
        if (nl) STG_B(0, 0, 128);
        SCB; LGKC(8); BAR; LGKC(0); SCB;
        SP1; QMFMA(aQ0, bQ0, 0, 0); SP0; SCB; BAR; SCB;
        // P6
        RD_AHI(1);
        if (nl) STG_B(0, 1, 128);
        SCB; BAR; LGKC(0); SCB;
        SP1; QMFMA(aQ1, bQ0, 4, 0); SP0; SCB; BAR; SCB;
        // P7' (merged): 32-MFMA cluster
        RD_BHI(1);
        if (nl) { STG_A(1, 0, 192); STG_A(1, 1, 192); }
        SCB; BAR; LGKC(0); SCB;
        SP1; QMFMA(aQ0, bQ1, 0, 2); QMFMA(aQ1, bQ1, 4, 2); SP0; SCB;
        if (nl) VMCNT(4);
        BAR; SCB;
        tofs += 128;
    }
}

// C/D layout per 16x16x32 frag (m89/m91): col = lane&15, row = 4*(lane>>4) + r
// global: row = tile_m + wm*128 + m*16 + 4*(lane>>4) + r ; col = tile_n + wn*64 + n*16 + (lane&15)

// ---- R8 merged prep kernel: maskbits FIRST (long-pole role overlaps with the rest),
// then convert (fp32->bf16), then wtrans. maskbits is unroll-4: 4 independent
// word-loads in flight per iteration (was 1 load -> ballot -> stall: latency-bound,
// 23% HBM). Each wave owns a contiguous 64-word (16 KB) mask slab for DRAM locality.
#define MB_BLKS   2048
#define CONV_BLKS 16384
#define CONV_END  (MB_BLKS + CONV_BLKS)
__global__ __launch_bounds__(256) void prep_kernel(const float* __restrict__ q,
                                                   const float* __restrict__ e,
                                                   const float* __restrict__ Wq,
                                                   const float* __restrict__ Wk,
                                                   const float* __restrict__ Wv,
                                                   const int* __restrict__ mask,
                                                   short* __restrict__ xq,
                                                   short* __restrict__ xe,
                                                   short* __restrict__ Wt,
                                                   unsigned long long* __restrict__ Mbits,
                                                   float* __restrict__ L) {
    __shared__ float tile[32][33];
    int bid = blockIdx.x, tid = threadIdx.x;
    if (bid < MB_BLKS) {
        // maskbits: int32 -> u64 ballot bitmask, + zero L. Wave g handles the
        // contiguous word range [g*64, g*64+64); 16 outer iters x 4 words in flight.
        int lane = tid & 63;
        if (bid < 64) L[bid * 256 + tid] = 0.f;
        int g = bid * 4 + (tid >> 6);
        const int* mp = mask + (size_t)g * 64 * 64;
        unsigned long long* op = Mbits + (size_t)g * 64;
#pragma unroll
        for (int i = 0; i < 16; ++i) {
            int v0 = mp[(i * 4 + 0) * 64 + lane];
            int v1 = mp[(i * 4 + 1) * 64 + lane];
            int v2 = mp[(i * 4 + 2) * 64 + lane];
            int v3 = mp[(i * 4 + 3) * 64 + lane];
            unsigned long long b0 = __ballot(v0 != 0);
            unsigned long long b1 = __ballot(v1 != 0);
            unsigned long long b2 = __ballot(v2 != 0);
            unsigned long long b3 = __ballot(v3 != 0);
            if (lane == 0) {
                op[i * 4 + 0] = b0; op[i * 4 + 1] = b1;
                op[i * 4 + 2] = b2; op[i * 4 + 3] = b3;
            }
        }
    } else if (bid < CONV_END) {
        // convert: 8 floats/thread
        int cb = bid - MB_BLKS;
        size_t i = (size_t)(cb & 8191) * 256 + tid;
        const float* src = (cb >> 13) ? e : q;
        short* dst = (cb >> 13) ? xe : xq;
        float4 a = ((const float4*)src)[2 * i];
        float4 b = ((const float4*)src)[2 * i + 1];
        short8 v;
        v[0] = f2bf(a.x); v[1] = f2bf(a.y); v[2] = f2bf(a.z); v[3] = f2bf(a.w);
        v[4] = f2bf(b.x); v[5] = f2bf(b.y); v[6] = f2bf(b.z); v[7] = f2bf(b.w);
        ((short8*)dst)[i] = v;
    } else {
        // wtrans: 32x32 tile transpose, z picks Wq/Wk/Wv
        int t = bid - CONV_END;
        int z = t >> 10, r2 = t & 1023;
        const float* W = (z == 0) ? Wq : (z == 1) ? Wk : Wv;
        short* dst = Wt + (size_t)z * HD * FD;
        int h0 = (r2 & 31) * 32, f0 = (r2 >> 5) * 32;
        int tx = tid & 31, ty = tid >> 5;
        for (int j = ty; j < 32; j += 8)
            tile[j][tx] = W[(size_t)(f0 + j) * HD + h0 + tx];
        __syncthreads();
        for (int j = ty; j < 32; j += 8)
            dst[(size_t)(h0 + j) * FD + f0 + tx] = f2bf(tile[tx][j]);
    }
}

// ---- Q/K projections: 256x256 tiles over [16384 x 1024] ----
__global__ __launch_bounds__(512, 2) void projqk_kernel(const short* __restrict__ Xq,
                                                        const short* __restrict__ Xe,
                                                        const short* __restrict__ Wt3,
                                                        const float* __restrict__ bq,
                                                        const float* __restrict__ bk,
                                                        short* __restrict__ Q,
                                                        short* __restrict__ K) {
    extern __shared__ char smem[];
    int tid = threadIdx.x;
    int p = blockIdx.z;
    const short* X = p ? Xe : Xq;
    const short* Wt = Wt3 + (size_t)p * HD * FD;
    const float* bias = p ? bk : bq;
    short* O = p ? K : Q;
    int bid = blockIdx.x;                   // XCD swizzle: m-groups bound to XCDs
    int xcd = bid & 7, idx = bid >> 3;
    int n_t = idx & 3, m_t = (idx >> 2) * 8 + xcd;
    int tile_m = m_t * 256, tile_n = n_t * 256;
    f32x4 acc[8][4] = {};
    gemm256_core<false>(X + (size_t)tile_m * FD, Wt + (size_t)tile_n * FD, FD, FD, smem, acc, tid);
    int wid = tid >> 6, lane = tid & 63;
    int wm = wid >> 2, wn = wid & 3;
    int row0 = tile_m + wm * 128 + ((lane >> 4) << 2);
    int col0 = tile_n + wn * 64 + (lane & 15);
    // n-INNER store order (write-combine; kills the 2x WRITE_SIZE amplification)
    float bv4[4];
#pragma unroll
    for (int n = 0; n < 4; ++n) bv4[n] = bias[col0 + n * 16];
#pragma unroll
    for (int m = 0; m < 8; ++m)
#pragma unroll
        for (int r = 0; r < 4; ++r) {
            size_t rowb = (size_t)(row0 + m * 16 + r) * HD;
#pragma unroll
            for (int n = 0; n < 4; ++n)
                O[rowb + col0 + n * 16] = f2bf(acc[m][n][r] + bv4[n]);
        }
}

// ---- V projection, transposed natively: Vt[b][h][t] = Wtv[h,:].Xe[b,t,:] + bv[h], fp16 out ----
__global__ __launch_bounds__(512, 2) void projv_kernel(const short* __restrict__ Xe,
                                                       const short* __restrict__ Wtv,
                                                       const float* __restrict__ bv,
                                                       short* __restrict__ Vt) {
    extern __shared__ char smem[];
    int tid = threadIdx.x;
    int bid = blockIdx.x;
    int b = bid & 7, i = bid >> 3;          // batch -> XCD binding
    int m_t = i & 3, n_t = i >> 2;          // m over HD (4), n over TKv (8)
    int tile_m = m_t * 256, tile_n = n_t * 256;
    const short* Xb = Xe + (size_t)b * TKv * FD;
    f32x4 acc[8][4] = {};
    gemm256_core<false>(Wtv + (size_t)tile_m * FD, Xb + (size_t)tile_n * FD, FD, FD, smem, acc, tid);
    short* Ob = Vt + (size_t)b * HD * TKv;
    int wid = tid >> 6, lane = tid & 63;
    int wm = wid >> 2, wn = wid & 3;
    int row0 = tile_m + wm * 128 + ((lane >> 4) << 2);
    int col0 = tile_n + wn * 64 + (lane & 15);
#pragma unroll
    for (int m = 0; m < 8; ++m)
#pragma unroll
        for (int r = 0; r < 4; ++r) {
            int gm = row0 + m * 16 + r;     // h
            float bv_ = bv[gm];
#pragma unroll
            for (int n = 0; n < 4; ++n) {
                union { _Float16 h; short s; } cv;
                cv.h = (_Float16)(acc[m][n][r] + bv_);
                Ob[(size_t)gm * TKv + col0 + n * 16] = cv.s;
            }
        }
}

// ---- score: P' = mask ? exp(QK/32 - 4) : 0 (fp16), row partials -> atomicAdd L ----
__global__ __launch_bounds__(512, 2) void score_kernel(const short* __restrict__ Q,
                                                       const short* __restrict__ K,
                                                       const unsigned long long* __restrict__ Mbits,
                                                       short* __restrict__ S,
                                                       float* __restrict__ L) {
    extern __shared__ char smem[];
    int tid = threadIdx.x;
    int bid = blockIdx.x;
    int b = bid & 7, i = bid >> 3;          // batch -> XCD binding
    int n_t = i & 7, m_t = i >> 3;
    int tile_m = m_t * 256, tile_n = n_t * 256;
    const short* Aq = Q + (size_t)b * TQv * HD;
    const short* Bk = K + (size_t)b * TKv * HD;
    f32x4 acc[8][4] = {};
    gemm256_core<false>(Aq + (size_t)tile_m * HD, Bk + (size_t)tile_n * HD, HD, HD, smem, acc, tid);
    short* Sb = S + (size_t)b * TQv * TKv;
    float* Lb = L + (size_t)b * TQv;
    int wid = tid >> 6, lane = tid & 63;
    int wm = wid >> 2, wn = wid & 3;
    int l15 = lane & 15;
    int row0 = tile_m + wm * 128 + ((lane >> 4) << 2);
    int col0 = tile_n + wn * 64 + l15;

    // stage this block's Mbits slab (256 rows x 4 words = 8 KB) into now-free LDS
    // with one coalesced global_load_lds burst (kills the serialized load chain).
    {
        const unsigned long long* MbT = Mbits + (size_t)b * TQv * (TKv / 64)
                                        + (size_t)tile_m * (TKv / 64) + (tile_n >> 6);
        async16((const short*)(MbT + (size_t)(tid >> 1) * (TKv / 64) + (size_t)(tid & 1) * 2),
                (short*)smem + wid * 512);
    }
    __syncthreads();   // drains vmcnt(0)+lgkmcnt(0): slab landed, visible to all

#pragma unroll
    for (int m = 0; m < 8; ++m)
#pragma unroll
        for (int r = 0; r < 4; ++r) {
            int rl = wm * 128 + m * 16 + ((lane >> 4) << 2) + r;   // row - tile_m
            int gm = tile_m + rl;
            unsigned long long bits = *(const unsigned long long*)(smem + rl * 32 + wn * 8);
            float rs = 0.f;
#pragma unroll
            for (int n = 0; n < 4; ++n) {
                // exp2((acc/32 - 4)*log2e) folded: exp2(acc*0.04508422 - 5.77078016)
                float pv = ((bits >> (n * 16 + l15)) & 1ULL)
                               ? exp2f(acc[m][n][r] * 0.04508422f - 5.77078016f) : 0.f;
                rs += pv;
                union { _Float16 h; short sh; } cv;
                cv.h = (_Float16)pv;
                Sb[(size_t)gm * TKv + col0 + n * 16] = cv.sh;
            }
            for (int sh = 1; sh < 16; sh <<= 1) rs += __shfl_xor(rs, sh);
            if (l15 == 0) atomicAdd(&Lb[gm], rs);
        }
}

// ---- pv: O = (P' . Vt^T) / L, fp16 MFMA, fp32 out ----
__global__ __launch_bounds__(512, 2) void pv_kernel(const short* __restrict__ P,
                                                    const short* __restrict__ Vt,
                                                    const float* __restrict__ L,
                                                    float* __restrict__ Out) {
    extern __shared__ char smem[];
    int tid = threadIdx.x;
    int bid = blockIdx.x;
    int b = bid & 7, i = bid >> 3;          // batch -> XCD binding
    int n_t = i & 3, m_t = i >> 2;          // n over HD (4), m over TQv (8)
    int tile_m = m_t * 256, tile_n = n_t * 256;
    const short* Ap = P + (size_t)b * TQv * TKv;
    const short* Bv = Vt + (size_t)b * HD * TKv;
    const float* Lb = L + (size_t)b * TQv;
    f32x4 acc[8][4] = {};
    gemm256_core<true>(Ap + (size_t)tile_m * TKv, Bv + (size_t)tile_n * TKv, TKv, TKv, smem, acc, tid);
    float* Ob = Out + (size_t)b * TQv * HD;
    int wid = tid >> 6, lane = tid & 63;
    int wm = wid >> 2, wn = wid & 3;
    int row0 = tile_m + wm * 128 + ((lane >> 4) << 2);
    int col0 = tile_n + wn * 64 + (lane & 15);

    // stage the 256-row L slab (1 KB) into free LDS via wave 0 (broadcast reads after)
    if (tid < 64)
        async16((const short*)(Lb + tile_m + tid * 4), (short*)smem);
    __syncthreads();

#pragma unroll
    for (int m = 0; m < 8; ++m)
#pragma unroll
        for (int r = 0; r < 4; ++r) {
            int rl = wm * 128 + m * 16 + ((lane >> 4) << 2) + r;   // row - tile_m
            int gm = tile_m + rl;
            float l = *(const float*)(smem + rl * 4);
            float inv = (l > 0.f) ? 1.f / l : 0.f;
#pragma unroll
            for (int n = 0; n < 4; ++n)
                Ob[(size_t)gm * HD + col0 + n * 16] = acc[m][n][r] * inv;
        }
}

extern "C" void kernel_launch(void* const* d_in, const int* in_sizes, int n_in,
                              void* d_out, int out_size, void* d_ws, size_t ws_size,
                              hipStream_t stream) {
    const float* query = (const float*)d_in[0];
    const float* enc   = (const float*)d_in[1];
    const int*   mask  = (const int*)d_in[2];
    const float* Wq    = (const float*)d_in[3];
    const float* bq    = (const float*)d_in[4];
    const float* Wk    = (const float*)d_in[5];
    const float* bk    = (const float*)d_in[6];
    const float* Wv    = (const float*)d_in[7];
    const float* bv    = (const float*)d_in[8];
    float* out = (float*)d_out;

    // workspace layout (bytes):
    //   Mbits [0,4MB), L [4MB,+64KB), Wt [4.0625MB,+6.29MB), Xq/Xe, S aliases Xq/Xe,
    //   Qb, Kb, Vt.
    char* ws = (char*)d_ws;
    unsigned long long* Mbits = (unsigned long long*)(ws);
    float* L   = (float*)(ws + 4194304);
    short* Wt  = (short*)(ws + 4259840);
    short* Xq  = (short*)(ws + 10551296);
    short* Xe  = (short*)(ws + 44105728);
    short* S   = (short*)(ws + 10551296);      // aliases Xq,Xe (dead after projqk/projv)
    short* Qb  = (short*)(ws + 77660160);
    short* Kb  = (short*)(ws + 111214592);
    short* Vt  = (short*)(ws + 144769024);
    (void)in_sizes; (void)n_in; (void)out_size; (void)ws_size;

    // 128 KiB dynamic LDS opt-in (one-time; not a stream op, graph-capture safe)
    static bool inited = false;
    if (!inited) {
        hipFuncSetAttribute((const void*)projqk_kernel, hipFuncAttributeMaxDynamicSharedMemorySize, 131072);
        hipFuncSetAttribute((const void*)projv_kernel,  hipFuncAttributeMaxDynamicSharedMemorySize, 131072);
        hipFuncSetAttribute((const void*)score_kernel,  hipFuncAttributeMaxDynamicSharedMemorySize, 131072);
        hipFuncSetAttribute((const void*)pv_kernel,     hipFuncAttributeMaxDynamicSharedMemorySize, 131072);
        inited = true;
    }

    prep_kernel<<<dim3(MB_BLKS + CONV_BLKS + 3072), 256, 0, stream>>>(
        query, enc, Wq, Wk, Wv, mask, Xq, Xe, Wt, Mbits, L);
    projqk_kernel<<<dim3(256, 1, 2), 512, 131072, stream>>>(Xq, Xe, Wt, bq, bk, Qb, Kb);
    projv_kernel<<<dim3(256), 512, 131072, stream>>>(Xe, Wt + (size_t)2 * HD * FD, bv, Vt);
    score_kernel<<<dim3(512), 512, 131072, stream>>>(Qb, Kb, Mbits, S, L);
    pv_kernel<<<dim3(256), 512, 131072, stream>>>(S, Vt, L, out);
}